// Round 1
// 436.132 us; speedup vs baseline: 1.0022x; 1.0022x over previous
//
#include <hip/hip_runtime.h>
#include <hip/hip_bf16.h>
#include <math.h>

#define N_NODES 50000
#define N_EDGES 1600000
#define NFEAT 512
#define NHID 128
#define NCLASS 40

#define NBUCKETS 196      // ceil(N_NODES / 256), dst>>8
#define BUCKET_CAP 16384  // avg fill ~8163 -> huge margin

typedef __attribute__((ext_vector_type(8))) short bf16x8;
typedef __attribute__((ext_vector_type(4))) float f32x4;

static __device__ __forceinline__ float asfloat_u32(unsigned int u) {
    union { unsigned int u; float f; } c;
    c.u = u;
    return c.f;
}
static __device__ __forceinline__ unsigned int asu32_f(float f) {
    union { float f; unsigned int u; } c;
    c.f = f;
    return c.u;
}
static __device__ __forceinline__ unsigned short f2bf(float f) {
    union { float f; unsigned int u; } c;
    c.f = f;
    unsigned int r = c.u + 0x7FFFu + ((c.u >> 16) & 1u);  // RTN-even
    return (unsigned short)(r >> 16);
}

// ---------------- prep: bucket cursor init + both weight transposes ----------------
__global__ __launch_bounds__(256) void prep_kernel(const float* __restrict__ W1,
                                                   unsigned short* __restrict__ Wt1,
                                                   const float* __restrict__ Wh,
                                                   unsigned short* __restrict__ Wth,
                                                   int* __restrict__ bucketCursor) {
    int idx = blockIdx.x * 256 + threadIdx.x;
    if (idx < NFEAT * NHID) {  // Wt1[n][k] = bf16(W1[k][n])
        int k = idx >> 7;
        int n = idx & 127;
        Wt1[(size_t)n * NFEAT + k] = f2bf(W1[idx]);
    } else if (idx < NFEAT * NHID + NHID * NHID) {
        int j = idx - NFEAT * NHID;
        int k = j >> 7;
        int n = j & 127;
        Wth[(size_t)n * NHID + k] = f2bf(Wh[j]);
    } else {
        int j = idx - (NFEAT * NHID + NHID * NHID);
        if (j < NBUCKETS) bucketCursor[j] = j * BUCKET_CAP;
    }
}

// ---------------- GEMM (64-row tile) body, N=128 ----------------
// C[M x 128](bf16) = A[M x K] @ Wt^T ; Wt is [128][K] bf16.
// 256 thr / 4 waves; wave w covers rows [w*16, w*16+16); 8 col MFMA tiles.
// LDS rows padded to LDP=40 bf16 (80B stride, <=2-way bank aliasing = free).
// Depth-2 register prefetch: loads for k-step it+2 are issued before computing
// step it, so HBM latency (~600-900cy) hides under ~2 compute+barrier phases.
// Grid is only ~4.6 blocks/CU (M-limited), so TLP cannot hide it -- ILP must.
#define LDP 40
#define GEMM_LDS_BYTES ((64 + 128) * LDP * 2)

template <bool A_IS_BF16>
static __device__ __forceinline__ void gemm64_body(const void* __restrict__ Ap,
                                                   const unsigned short* __restrict__ Wt,
                                                   unsigned short* __restrict__ C,
                                                   const int M, const int K,
                                                   char* smem, int bid) {
    unsigned short* As = (unsigned short*)smem;             // 64 x LDP
    unsigned short* Bs = (unsigned short*)smem + 64 * LDP;  // 128 x LDP
    const int tid = threadIdx.x;
    const int wave = tid >> 6;
    const int lane = tid & 63;
    const int ln = lane & 15;
    const int quad = lane >> 4;
    const int row0 = bid * 64;

    const int ar = tid >> 2;            // A staging row 0..63
    const int ac = (tid & 3) * 8;       // A staging k-offset
    const bool arOk = (row0 + ar) < M;
    const int bn = tid >> 1;            // B staging col(n) 0..127
    const int bk = (tid & 1) * 16;      // B staging k-offset (16 elems = 2x bf16x8)

    const unsigned short* Abf = (const unsigned short*)Ap + (size_t)(row0 + ar) * K + ac;
    const float* Af = (const float*)Ap + (size_t)(row0 + ar) * K + ac;
    const unsigned short* Bg = Wt + (size_t)bn * K + bk;

    f32x4 acc[8];
#pragma unroll
    for (int t = 0; t < 8; ++t) acc[t] = (f32x4){0.f, 0.f, 0.f, 0.f};

    const int NK = K >> 5;  // k-steps of 32; always even here (16 or 4)

    // Two prefetch stages with STATIC register names (runtime-indexed arrays
    // of ext_vector types spill to scratch -- rule #20).
    bf16x8 vaA, vaB;                      // bf16-A path
    float4 faA0, faA1, faB0, faB1;        // f32-A path
    bf16x8 vb0A, vb1A, vb0B, vb1B;

#define G64_ISSUE(kc, va_, fa0_, fa1_, vb0_, vb1_)                         \
    do {                                                                   \
        if (A_IS_BF16) {                                                   \
            if (arOk) va_ = *(const bf16x8*)(Abf + (kc));                  \
        } else {                                                           \
            if (arOk) {                                                    \
                fa0_ = *(const float4*)(Af + (kc));                        \
                fa1_ = *(const float4*)(Af + (kc) + 4);                    \
            }                                                              \
        }                                                                  \
        vb0_ = *(const bf16x8*)(Bg + (kc));                                \
        vb1_ = *(const bf16x8*)(Bg + (kc) + 8);                            \
    } while (0)

#define G64_STAGE(va_, fa0_, fa1_, vb0_, vb1_)                             \
    do {                                                                   \
        bf16x8 vw;                                                         \
        if (A_IS_BF16) {                                                   \
            if (arOk) {                                                    \
                vw = va_;                                                  \
            } else {                                                       \
                _Pragma("unroll") for (int i = 0; i < 8; ++i) vw[i] = 0;   \
            }                                                              \
        } else {                                                           \
            if (arOk) {                                                    \
                vw[0] = (short)f2bf(fa0_.x); vw[1] = (short)f2bf(fa0_.y);  \
                vw[2] = (short)f2bf(fa0_.z); vw[3] = (short)f2bf(fa0_.w);  \
                vw[4] = (short)f2bf(fa1_.x); vw[5] = (short)f2bf(fa1_.y);  \
                vw[6] = (short)f2bf(fa1_.z); vw[7] = (short)f2bf(fa1_.w);  \
            } else {                                                       \
                _Pragma("unroll") for (int i = 0; i < 8; ++i) vw[i] = 0;   \
            }                                                              \
        }                                                                  \
        *(bf16x8*)&As[ar * LDP + ac] = vw;                                 \
        *(bf16x8*)&Bs[bn * LDP + bk] = vb0_;                               \
        *(bf16x8*)&Bs[bn * LDP + bk + 8] = vb1_;                           \
    } while (0)

#define G64_COMPUTE()                                                          \
    do {                                                                       \
        bf16x8 a = *(const bf16x8*)&As[(wave * 16 + ln) * LDP + quad * 8];     \
        _Pragma("unroll") for (int t = 0; t < 8; ++t) {                        \
            bf16x8 b = *(const bf16x8*)&Bs[(t * 16 + ln) * LDP + quad * 8];    \
            acc[t] = __builtin_amdgcn_mfma_f32_16x16x32_bf16(a, b, acc[t], 0, 0, 0); \
        }                                                                      \
    } while (0)

    G64_ISSUE(0, vaA, faA0, faA1, vb0A, vb1A);
    G64_ISSUE(32, vaB, faB0, faB1, vb0B, vb1B);

    for (int it = 0; it < NK; it += 2) {
        __syncthreads();  // previous step's LDS reads done
        G64_STAGE(vaA, faA0, faA1, vb0A, vb1A);
        __syncthreads();
        if (it + 2 < NK) G64_ISSUE((it + 2) * 32, vaA, faA0, faA1, vb0A, vb1A);
        G64_COMPUTE();

        __syncthreads();
        G64_STAGE(vaB, faB0, faB1, vb0B, vb1B);
        __syncthreads();
        if (it + 3 < NK) G64_ISSUE((it + 3) * 32, vaB, faB0, faB1, vb0B, vb1B);
        G64_COMPUTE();
    }

#undef G64_ISSUE
#undef G64_STAGE
#undef G64_COMPUTE

#pragma unroll
    for (int t = 0; t < 8; ++t) {
#pragma unroll
        for (int r = 0; r < 4; ++r) {
            int row = row0 + wave * 16 + quad * 4 + r;
            if (row < M) C[(size_t)row * 128 + t * 16 + ln] = f2bf(acc[t][r]);
        }
    }
}

// ---------------- bin body: bucket edges by dst>>8 ----------------
// Record: x = src | (dstLow8)<<16 ; y = fp32 weight bits.
static __device__ __forceinline__ void bin_body(const int* __restrict__ src,
                                                const int* __restrict__ dst,
                                                const float* __restrict__ w,
                                                int* __restrict__ bucketCursor,
                                                uint2* __restrict__ binned,
                                                int n, char* smem, int bid) {
    int* hist = (int*)smem;            // NBUCKETS
    int* cur = (int*)smem + NBUCKETS;  // NBUCKETS
    const int tid = threadIdx.x;
    const int base = bid * 4096;
    if (tid < NBUCKETS) hist[tid] = 0;
    __syncthreads();
#pragma unroll
    for (int r = 0; r < 16; ++r) {
        int e = base + r * 256 + tid;
        if (e < n) atomicAdd(&hist[dst[e] >> 8], 1);
    }
    __syncthreads();
    if (tid < NBUCKETS && hist[tid] > 0)
        cur[tid] = atomicAdd(&bucketCursor[tid], hist[tid]);
    __syncthreads();
#pragma unroll
    for (int r = 0; r < 16; ++r) {
        int e = base + r * 256 + tid;
        if (e < n) {
            int d = dst[e];
            int pos = atomicAdd(&cur[d >> 8], 1);
            uint2 rec;
            rec.x = (unsigned int)src[e] | ((unsigned int)(d & 255) << 16);
            rec.y = asu32_f(w[e]);
            binned[pos] = rec;
        }
    }
}

// ---------------- fused: GEMM1 (782 blocks) || bin (391 blocks) ----------------
#define GEMM1_BLOCKS 782
#define BIN_BLOCKS 391
__global__ __launch_bounds__(256) void fused_gemm1_bin(const float* __restrict__ x,
                                                       const unsigned short* __restrict__ Wt1,
                                                       unsigned short* __restrict__ tb,
                                                       const int* __restrict__ src,
                                                       const int* __restrict__ dst,
                                                       const float* __restrict__ w,
                                                       int* __restrict__ bucketCursor,
                                                       uint2* __restrict__ binned) {
    __shared__ char smem[GEMM_LDS_BYTES];
    if (blockIdx.x < GEMM1_BLOCKS) {
        gemm64_body<false>(x, Wt1, tb, N_NODES, NFEAT, smem, blockIdx.x);
    } else {
        bin_body(src, dst, w, bucketCursor, binned, N_EDGES, smem,
                 blockIdx.x - GEMM1_BLOCKS);
    }
}

// ---------------- standalone GEMM layer 2 ----------------
__global__ __launch_bounds__(256) void gemm64_l2(const unsigned short* __restrict__ A,
                                                 const unsigned short* __restrict__ Wt,
                                                 unsigned short* __restrict__ C) {
    __shared__ char smem[GEMM_LDS_BYTES];
    gemm64_body<true>(A, Wt, C, N_NODES, NHID, smem, blockIdx.x);
}

// ---------------- build_csr (inline bucket scan): 4B edge records ----------------
// pairs[pos] = src(16b) | bf16(weight)(16b high)
__global__ __launch_bounds__(256) void build_csr(const uint2* __restrict__ binned,
                                                 const int* __restrict__ bucketCursor,
                                                 unsigned int* __restrict__ pairs,
                                                 int* __restrict__ row_ptr) {
    __shared__ int bs[256];
    __shared__ int hist[256];
    __shared__ int sc[256];
    __shared__ int cur[256];
    const int b = blockIdx.x;
    const int tid = threadIdx.x;

    // inline exclusive scan of bucket fills
    int c = (tid < NBUCKETS) ? (bucketCursor[tid] - tid * BUCKET_CAP) : 0;
    bs[tid] = c;
    __syncthreads();
    for (int off = 1; off < 256; off <<= 1) {
        int t = (tid >= off) ? bs[tid - off] : 0;
        __syncthreads();
        bs[tid] += t;
        __syncthreads();
    }
    const int cnt = bucketCursor[b] - b * BUCKET_CAP;
    const int segStart = bs[b] - cnt;  // exclusive prefix at b
    if (b == NBUCKETS - 1 && tid == 0) row_ptr[N_NODES] = bs[NBUCKETS - 1];
    const uint2* seg = binned + (size_t)b * BUCKET_CAP;

    hist[tid] = 0;
    __syncthreads();
    for (int i = tid; i < cnt; i += 256)
        atomicAdd(&hist[seg[i].x >> 16], 1);
    __syncthreads();
    int v = hist[tid];
    sc[tid] = v;
    __syncthreads();
    for (int off = 1; off < 256; off <<= 1) {
        int t = (tid >= off) ? sc[tid - off] : 0;
        __syncthreads();
        sc[tid] += t;
        __syncthreads();
    }
    int excl = sc[tid] - v;
    int node = b * 256 + tid;
    if (node < N_NODES) row_ptr[node] = segStart + excl;
    cur[tid] = segStart + excl;
    __syncthreads();
    for (int i = tid; i < cnt; i += 256) {
        uint2 p = seg[i];
        int pos = atomicAdd(&cur[p.x >> 16], 1);
        pairs[pos] = (p.x & 0xFFFFu) | ((unsigned int)f2bf(asfloat_u32(p.y)) << 16);
    }
}

// ---------------- GEMM, N=40, K=128, A bf16 -> C bf16 ----------------
__global__ __launch_bounds__(256) void gemm_n40_bf16A(const unsigned short* __restrict__ A,
                                                      const float* __restrict__ Bm,
                                                      unsigned short* __restrict__ C, int M) {
    __shared__ float As[64][132];
    __shared__ float Bs[128 * 40];
    const int tid = threadIdx.x;
    const int tr = tid >> 2;
    const int tc = tid & 3;
    const int row0 = blockIdx.x * 64;

#pragma unroll
    for (int q = tid; q < 2048; q += 256) {
        int r = q >> 5;
        int c = (q & 31) << 2;
        int row = row0 + r;
        uint2 u = make_uint2(0u, 0u);
        if (row < M) u = *(const uint2*)(A + (size_t)row * 128 + c);
        As[r][c + 0] = asfloat_u32(u.x << 16);
        As[r][c + 1] = asfloat_u32(u.x & 0xFFFF0000u);
        As[r][c + 2] = asfloat_u32(u.y << 16);
        As[r][c + 3] = asfloat_u32(u.y & 0xFFFF0000u);
    }
    for (int q = tid; q < 128 * 40; q += 256) Bs[q] = Bm[q];
    __syncthreads();

    float acc[10];
#pragma unroll
    for (int j = 0; j < 10; ++j) acc[j] = 0.f;

    for (int k = 0; k < 128; ++k) {
        float a = As[tr][k];
#pragma unroll
        for (int j = 0; j < 10; ++j) acc[j] += a * Bs[k * 40 + tc * 10 + j];
    }

    int row = row0 + tr;
    if (row < M) {
#pragma unroll
        for (int j = 0; j < 10; ++j) C[(size_t)row * 40 + tc * 10 + j] = f2bf(acc[j]);
    }
}

// ---------------- SpMM (CSR gather, bf16 rows) + bias + ReLU, feat=128 ----------------
// One wave per dst node, split into two 32-lane halves: half h gathers edge
// e+2i+h with uint2 (8B = 4 feats) per lane -> 16 edges in flight per wave
// (2x the MLP of the 4B/lane version), same 256B/row coalescing. Cross-half
// feature sums combined with __shfl_xor(.,32) at the end.
__global__ __launch_bounds__(256) void spmm_bias_relu_bf16(const unsigned short* __restrict__ t,
                                                           const int* __restrict__ row_ptr,
                                                           const unsigned int* __restrict__ pairs,
                                                           const float* __restrict__ bias,
                                                           unsigned short* __restrict__ out) {
    const int node = blockIdx.x * 4 + (threadIdx.x >> 6);
    const int lane = threadIdx.x & 63;
    const int half = lane >> 5;
    const int fq = (lane & 31) * 4;  // feature base (4 bf16 = 8B) owned by this lane
    const int e0 = row_ptr[node];
    const int e1 = row_ptr[node + 1];
    float a0 = 0.f, a1 = 0.f, a2 = 0.f, a3 = 0.f;
    int e = e0;
    for (; e + 16 <= e1; e += 16) {
        unsigned int p[8];
        uint2 v[8];
#pragma unroll
        for (int i = 0; i < 8; ++i) p[i] = pairs[e + 2 * i + half];
#pragma unroll
        for (int i = 0; i < 8; ++i)
            v[i] = *(const uint2*)(t + (size_t)(p[i] & 0xFFFFu) * 128 + fq);
#pragma unroll
        for (int i = 0; i < 8; ++i) {
            float w = asfloat_u32(p[i] & 0xFFFF0000u);
            a0 += w * asfloat_u32(v[i].x << 16);
            a1 += w * asfloat_u32(v[i].x & 0xFFFF0000u);
            a2 += w * asfloat_u32(v[i].y << 16);
            a3 += w * asfloat_u32(v[i].y & 0xFFFF0000u);
        }
    }
    for (; e + 2 <= e1; e += 2) {
        unsigned int p = pairs[e + half];
        uint2 v = *(const uint2*)(t + (size_t)(p & 0xFFFFu) * 128 + fq);
        float w = asfloat_u32(p & 0xFFFF0000u);
        a0 += w * asfloat_u32(v.x << 16);
        a1 += w * asfloat_u32(v.x & 0xFFFF0000u);
        a2 += w * asfloat_u32(v.y << 16);
        a3 += w * asfloat_u32(v.y & 0xFFFF0000u);
    }
    if (e < e1 && half == 0) {  // odd trailing edge: half 0 only
        unsigned int p = pairs[e];
        uint2 v = *(const uint2*)(t + (size_t)(p & 0xFFFFu) * 128 + fq);
        float w = asfloat_u32(p & 0xFFFF0000u);
        a0 += w * asfloat_u32(v.x << 16);
        a1 += w * asfloat_u32(v.x & 0xFFFF0000u);
        a2 += w * asfloat_u32(v.y << 16);
        a3 += w * asfloat_u32(v.y & 0xFFFF0000u);
    }
    // combine the two halves (lane l and l+32 own the same 4 features)
    a0 += __shfl_xor(a0, 32);
    a1 += __shfl_xor(a1, 32);
    a2 += __shfl_xor(a2, 32);
    a3 += __shfl_xor(a3, 32);
    if (half == 0) {
        float4 b = *(const float4*)&bias[fq];
        a0 = fmaxf(a0 + b.x, 0.f);
        a1 = fmaxf(a1 + b.y, 0.f);
        a2 = fmaxf(a2 + b.z, 0.f);
        a3 = fmaxf(a3 + b.w, 0.f);
        uint2 o;
        o.x = ((unsigned int)f2bf(a0)) | (((unsigned int)f2bf(a1)) << 16);
        o.y = ((unsigned int)f2bf(a2)) | (((unsigned int)f2bf(a3)) << 16);
        *(uint2*)(out + (size_t)node * 128 + fq) = o;
    }
}

// ---------------- SpMM feat=40 (bf16 rows) + bias + log_softmax ----------------
__global__ __launch_bounds__(256) void spmm_logsoftmax(const unsigned short* __restrict__ t,
                                                       const int* __restrict__ row_ptr,
                                                       const unsigned int* __restrict__ pairs,
                                                       const float* __restrict__ bias,
                                                       float* __restrict__ out) {
    const int node = blockIdx.x * 4 + (threadIdx.x >> 6);
    const int lane = threadIdx.x & 63;
    const int e0 = row_ptr[node];
    const int e1 = row_ptr[node + 1];
    const bool act = lane < NCLASS;
    float acc = 0.f;
    int e = e0;
    for (; e + 4 <= e1; e += 4) {
        unsigned int p0 = pairs[e], p1 = pairs[e + 1], p2 = pairs[e + 2], p3 = pairs[e + 3];
        if (act) {
            float v0 = asfloat_u32((unsigned int)t[(size_t)(p0 & 0xFFFFu) * NCLASS + lane] << 16);
            float v1 = asfloat_u32((unsigned int)t[(size_t)(p1 & 0xFFFFu) * NCLASS + lane] << 16);
            float v2 = asfloat_u32((unsigned int)t[(size_t)(p2 & 0xFFFFu) * NCLASS + lane] << 16);
            float v3 = asfloat_u32((unsigned int)t[(size_t)(p3 & 0xFFFFu) * NCLASS + lane] << 16);
            acc += asfloat_u32(p0 & 0xFFFF0000u) * v0 + asfloat_u32(p1 & 0xFFFF0000u) * v1 +
                   asfloat_u32(p2 & 0xFFFF0000u) * v2 + asfloat_u32(p3 & 0xFFFF0000u) * v3;
        }
    }
    for (; e < e1; ++e) {
        unsigned int p = pairs[e];
        if (act)
            acc += asfloat_u32(p & 0xFFFF0000u) *
                   asfloat_u32((unsigned int)t[(size_t)(p & 0xFFFFu) * NCLASS + lane] << 16);
    }
    float logit = act ? (acc + bias[lane]) : -INFINITY;
    float m = logit;
#pragma unroll
    for (int off = 32; off; off >>= 1) m = fmaxf(m, __shfl_xor(m, off));
    float ex = act ? __expf(logit - m) : 0.f;
    float ssum = ex;
#pragma unroll
    for (int off = 32; off; off >>= 1) ssum += __shfl_xor(ssum, off);
    if (act) out[(size_t)node * NCLASS + lane] = logit - m - __logf(ssum);
}

// ---------------- launch ----------------

extern "C" void kernel_launch(void* const* d_in, const int* in_sizes, int n_in,
                              void* d_out, int out_size, void* d_ws, size_t ws_size,
                              hipStream_t stream) {
    const float* x = (const float*)d_in[0];
    const int* edge_src = (const int*)d_in[1];
    const int* edge_dst = (const int*)d_in[2];
    const float* edge_weight = (const float*)d_in[3];
    const float* W1 = (const float*)d_in[4];
    const float* b1 = (const float*)d_in[5];
    const float* Wh = (const float*)d_in[6];
    const float* bh = (const float*)d_in[7];
    const float* W2 = (const float*)d_in[8];
    const float* b2 = (const float*)d_in[9];
    float* out = (float*)d_out;

    size_t off = 0;
    auto carve = [&](size_t bytes) {
        void* p = (char*)d_ws + off;
        off += (bytes + 511) & ~(size_t)511;
        return p;
    };
    unsigned short* tb = (unsigned short*)carve((size_t)N_NODES * 128 * 2);
    unsigned short* hb = (unsigned short*)carve((size_t)N_NODES * 128 * 2);
    unsigned short* t3 = (unsigned short*)carve((size_t)N_NODES * NCLASS * 2);
    unsigned short* Wt1 = (unsigned short*)carve((size_t)NFEAT * NHID * 2);
    unsigned short* Wth = (unsigned short*)carve((size_t)NHID * NHID * 2);
    int* row_ptr = (int*)carve((size_t)(N_NODES + 4) * 4);
    int* bucketCursor = (int*)carve((size_t)NBUCKETS * 4);
    uint2* binned = (uint2*)carve((size_t)NBUCKETS * BUCKET_CAP * 8);
    unsigned int* pairs = (unsigned int*)carve((size_t)N_EDGES * 4);
    (void)ws_size; (void)n_in; (void)in_sizes; (void)out_size;

    const int prepBlocks = (NFEAT * NHID + NHID * NHID + NBUCKETS + 255) / 256;  // 321
    const int spmmBlocks = N_NODES / 4;            // 12500
    const int gemmBlocks = (N_NODES + 63) / 64;    // 782

    // prep (weights + cursors)
    prep_kernel<<<prepBlocks, 256, 0, stream>>>(W1, Wt1, Wh, Wth, bucketCursor);

    // GEMM1 || bin (independent work fused into one launch)
    fused_gemm1_bin<<<GEMM1_BLOCKS + BIN_BLOCKS, 256, 0, stream>>>(
        x, Wt1, tb, edge_src, edge_dst, edge_weight, bucketCursor, binned);

    // CSR finalize (inline bucket scan)
    build_csr<<<NBUCKETS, 256, 0, stream>>>(binned, bucketCursor, pairs, row_ptr);

    // Layer 1 aggregate
    spmm_bias_relu_bf16<<<spmmBlocks, 256, 0, stream>>>(tb, row_ptr, pairs, b1, hb);

    // Layer 2
    gemm64_l2<<<gemmBlocks, 256, 0, stream>>>(hb, Wth, tb);
    spmm_bias_relu_bf16<<<spmmBlocks, 256, 0, stream>>>(tb, row_ptr, pairs, bh, hb);

    // Layer 3
    gemm_n40_bf16A<<<gemmBlocks, 256, 0, stream>>>(hb, W2, t3, N_NODES);
    spmm_logsoftmax<<<spmmBlocks, 256, 0, stream>>>(t3, row_ptr, pairs, b2, out);
}

// Round 2
// 396.466 us; speedup vs baseline: 1.1025x; 1.1001x over previous
//
#include <hip/hip_runtime.h>
#include <hip/hip_bf16.h>
#include <math.h>

#define N_NODES 50000
#define N_EDGES 1600000
#define NFEAT 512
#define NHID 128
#define NCLASS 40

#define NBUCKETS 196      // ceil(N_NODES / 256), dst>>8
#define BUCKET_CAP 16384  // avg fill ~8163 -> huge margin

typedef __attribute__((ext_vector_type(8))) short bf16x8;
typedef __attribute__((ext_vector_type(4))) float f32x4;

static __device__ __forceinline__ float asfloat_u32(unsigned int u) {
    union { unsigned int u; float f; } c;
    c.u = u;
    return c.f;
}
static __device__ __forceinline__ unsigned int asu32_f(float f) {
    union { float f; unsigned int u; } c;
    c.f = f;
    return c.u;
}
static __device__ __forceinline__ unsigned short f2bf(float f) {
    union { float f; unsigned int u; } c;
    c.f = f;
    unsigned int r = c.u + 0x7FFFu + ((c.u >> 16) & 1u);  // RTN-even
    return (unsigned short)(r >> 16);
}

// ---------------- prep: bucket cursors + weight transposes (W1, Wh, W2) ----------------
// Wt2 is [64][128] bf16: Wt2[n][k] = W2[k][n] for n<40, 0 for 40<=n<64 (MFMA col padding).
__global__ __launch_bounds__(256) void prep_kernel(const float* __restrict__ W1,
                                                   unsigned short* __restrict__ Wt1,
                                                   const float* __restrict__ Wh,
                                                   unsigned short* __restrict__ Wth,
                                                   const float* __restrict__ W2,
                                                   unsigned short* __restrict__ Wt2,
                                                   int* __restrict__ bucketCursor) {
    int idx = blockIdx.x * 256 + threadIdx.x;
    if (idx < NFEAT * NHID) {  // Wt1[n][k] = bf16(W1[k][n])
        int k = idx >> 7;
        int n = idx & 127;
        Wt1[(size_t)n * NFEAT + k] = f2bf(W1[idx]);
    } else if (idx < NFEAT * NHID + NHID * NHID) {
        int j = idx - NFEAT * NHID;
        int k = j >> 7;
        int n = j & 127;
        Wth[(size_t)n * NHID + k] = f2bf(Wh[j]);
    } else if (idx < NFEAT * NHID + NHID * NHID + 64 * NHID) {
        int j = idx - (NFEAT * NHID + NHID * NHID);
        int n = j & 63;
        int k = j >> 6;
        Wt2[(size_t)n * NHID + k] = (n < NCLASS) ? f2bf(W2[(size_t)k * NCLASS + n]) : 0;
    } else {
        int j = idx - (NFEAT * NHID + NHID * NHID + 64 * NHID);
        if (j < NBUCKETS) bucketCursor[j] = j * BUCKET_CAP;
    }
}

// ---------------- GEMM (64-row tile) body, N=128 ---- round-0 proven version ----------
// C[M x 128](bf16) = A[M x K] @ Wt^T ; Wt is [128][K] bf16.
// 256 thr / 4 waves; wave w covers rows [w*16, w*16+16); 8 col MFMA tiles.
// LDS rows padded to LDP=40 bf16 (80B stride, <=2-way bank aliasing = free).
// NOTE: depth-2 register prefetch was tried (r1) and REGRESSED 80.5->84us --
// the compiler already pipelines the pre-barrier loads; keep the simple loop.
#define LDP 40
#define GEMM_LDS_BYTES ((64 + 128) * LDP * 2)

template <bool A_IS_BF16>
static __device__ __forceinline__ void gemm64_body(const void* __restrict__ Ap,
                                                   const unsigned short* __restrict__ Wt,
                                                   unsigned short* __restrict__ C,
                                                   const int M, const int K,
                                                   char* smem, int bid) {
    unsigned short* As = (unsigned short*)smem;             // 64 x LDP
    unsigned short* Bs = (unsigned short*)smem + 64 * LDP;  // 128 x LDP
    const int tid = threadIdx.x;
    const int wave = tid >> 6;
    const int lane = tid & 63;
    const int ln = lane & 15;
    const int quad = lane >> 4;
    const int row0 = bid * 64;

    const int ar = tid >> 2;            // A staging row 0..63
    const int ac = (tid & 3) * 8;       // A staging k-offset
    const bool arOk = (row0 + ar) < M;
    const int bn = tid >> 1;            // B staging col(n) 0..127
    const int bk = (tid & 1) * 16;      // B staging k-offset (16 elems = 2x bf16x8)

    f32x4 acc[8];
#pragma unroll
    for (int t = 0; t < 8; ++t) acc[t] = (f32x4){0.f, 0.f, 0.f, 0.f};

    for (int kc = 0; kc < K; kc += 32) {
        bf16x8 va;
        if (A_IS_BF16) {
            if (arOk) {
                va = *(const bf16x8*)((const unsigned short*)Ap +
                                      (size_t)(row0 + ar) * K + kc + ac);
            } else {
#pragma unroll
                for (int i = 0; i < 8; ++i) va[i] = 0;
            }
        } else {
            if (arOk) {
                const float* Af = (const float*)Ap + (size_t)(row0 + ar) * K + kc + ac;
                float4 f0 = *(const float4*)(Af);
                float4 f1 = *(const float4*)(Af + 4);
                va[0] = (short)f2bf(f0.x); va[1] = (short)f2bf(f0.y);
                va[2] = (short)f2bf(f0.z); va[3] = (short)f2bf(f0.w);
                va[4] = (short)f2bf(f1.x); va[5] = (short)f2bf(f1.y);
                va[6] = (short)f2bf(f1.z); va[7] = (short)f2bf(f1.w);
            } else {
#pragma unroll
                for (int i = 0; i < 8; ++i) va[i] = 0;
            }
        }
        const unsigned short* Bg = Wt + (size_t)bn * K + kc + bk;
        bf16x8 vb0 = *(const bf16x8*)Bg;
        bf16x8 vb1 = *(const bf16x8*)(Bg + 8);

        __syncthreads();  // previous iteration's compute done
        *(bf16x8*)&As[ar * LDP + ac] = va;
        *(bf16x8*)&Bs[bn * LDP + bk] = vb0;
        *(bf16x8*)&Bs[bn * LDP + bk + 8] = vb1;
        __syncthreads();

        bf16x8 a = *(const bf16x8*)&As[(wave * 16 + ln) * LDP + quad * 8];
#pragma unroll
        for (int t = 0; t < 8; ++t) {
            bf16x8 b = *(const bf16x8*)&Bs[(t * 16 + ln) * LDP + quad * 8];
            acc[t] = __builtin_amdgcn_mfma_f32_16x16x32_bf16(a, b, acc[t], 0, 0, 0);
        }
    }

#pragma unroll
    for (int t = 0; t < 8; ++t) {
#pragma unroll
        for (int r = 0; r < 4; ++r) {
            int row = row0 + wave * 16 + quad * 4 + r;
            if (row < M) C[(size_t)row * 128 + t * 16 + ln] = f2bf(acc[t][r]);
        }
    }
}

// ---------------- bin body: bucket edges by dst>>8 ----------------
// Record: x = src | (dstLow8)<<16 ; y = fp32 weight bits.
static __device__ __forceinline__ void bin_body(const int* __restrict__ src,
                                                const int* __restrict__ dst,
                                                const float* __restrict__ w,
                                                int* __restrict__ bucketCursor,
                                                uint2* __restrict__ binned,
                                                int n, char* smem, int bid) {
    int* hist = (int*)smem;            // NBUCKETS
    int* cur = (int*)smem + NBUCKETS;  // NBUCKETS
    const int tid = threadIdx.x;
    const int base = bid * 4096;
    if (tid < NBUCKETS) hist[tid] = 0;
    __syncthreads();
#pragma unroll
    for (int r = 0; r < 16; ++r) {
        int e = base + r * 256 + tid;
        if (e < n) atomicAdd(&hist[dst[e] >> 8], 1);
    }
    __syncthreads();
    if (tid < NBUCKETS && hist[tid] > 0)
        cur[tid] = atomicAdd(&bucketCursor[tid], hist[tid]);
    __syncthreads();
#pragma unroll
    for (int r = 0; r < 16; ++r) {
        int e = base + r * 256 + tid;
        if (e < n) {
            int d = dst[e];
            int pos = atomicAdd(&cur[d >> 8], 1);
            uint2 rec;
            rec.x = (unsigned int)src[e] | ((unsigned int)(d & 255) << 16);
            rec.y = asu32_f(w[e]);
            binned[pos] = rec;
        }
    }
}

// ---------------- fused: GEMM1 (782 blocks) || bin (391 blocks) ----------------
#define GEMM1_BLOCKS 782
#define BIN_BLOCKS 391
__global__ __launch_bounds__(256) void fused_gemm1_bin(const float* __restrict__ x,
                                                       const unsigned short* __restrict__ Wt1,
                                                       unsigned short* __restrict__ tb,
                                                       const int* __restrict__ src,
                                                       const int* __restrict__ dst,
                                                       const float* __restrict__ w,
                                                       int* __restrict__ bucketCursor,
                                                       uint2* __restrict__ binned) {
    __shared__ char smem[GEMM_LDS_BYTES];
    if (blockIdx.x < GEMM1_BLOCKS) {
        gemm64_body<false>(x, Wt1, tb, N_NODES, NFEAT, smem, blockIdx.x);
    } else {
        bin_body(src, dst, w, bucketCursor, binned, N_EDGES, smem,
                 blockIdx.x - GEMM1_BLOCKS);
    }
}

// ---------------- standalone GEMM layer 2 ----------------
__global__ __launch_bounds__(256) void gemm64_l2(const unsigned short* __restrict__ A,
                                                 const unsigned short* __restrict__ Wt,
                                                 unsigned short* __restrict__ C) {
    __shared__ char smem[GEMM_LDS_BYTES];
    gemm64_body<true>(A, Wt, C, N_NODES, NHID, smem, blockIdx.x);
}

// ---------------- build_csr (inline bucket scan): 4B edge records ----------------
// pairs[pos] = src(16b) | bf16(weight)(16b high)
// 1024 threads/block: 196 blocks = 0.77 blocks/CU, so per-block latency IS the
// kernel duration -- 4x threads = 4x fewer serial iterations per block.
__global__ __launch_bounds__(1024) void build_csr(const uint2* __restrict__ binned,
                                                  const int* __restrict__ bucketCursor,
                                                  unsigned int* __restrict__ pairs,
                                                  int* __restrict__ row_ptr) {
    __shared__ int bs[256];
    __shared__ int hist[256];
    __shared__ int sc[256];
    __shared__ int cur[256];
    const int b = blockIdx.x;
    const int tid = threadIdx.x;

    // inline exclusive scan of bucket fills (tid<256 participate; all sync)
    if (tid < 256) bs[tid] = (tid < NBUCKETS) ? (bucketCursor[tid] - tid * BUCKET_CAP) : 0;
    if (tid < 256) hist[tid] = 0;
    __syncthreads();
    for (int off = 1; off < 256; off <<= 1) {
        int t = 0;
        if (tid < 256 && tid >= off) t = bs[tid - off];
        __syncthreads();
        if (tid < 256) bs[tid] += t;
        __syncthreads();
    }
    const int cnt = bucketCursor[b] - b * BUCKET_CAP;
    const int segStart = bs[b] - cnt;  // exclusive prefix at b
    if (b == NBUCKETS - 1 && tid == 0) row_ptr[N_NODES] = bs[NBUCKETS - 1];
    const uint2* seg = binned + (size_t)b * BUCKET_CAP;

    for (int i = tid; i < cnt; i += 1024)
        atomicAdd(&hist[seg[i].x >> 16], 1);
    __syncthreads();
    if (tid < 256) {
        int v = hist[tid];
        sc[tid] = v;
    }
    __syncthreads();
    for (int off = 1; off < 256; off <<= 1) {
        int t = 0;
        if (tid < 256 && tid >= off) t = sc[tid - off];
        __syncthreads();
        if (tid < 256) sc[tid] += t;
        __syncthreads();
    }
    if (tid < 256) {
        int excl = sc[tid] - hist[tid];
        int node = b * 256 + tid;
        if (node < N_NODES) row_ptr[node] = segStart + excl;
        cur[tid] = segStart + excl;
    }
    __syncthreads();
    for (int i = tid; i < cnt; i += 1024) {
        uint2 p = seg[i];
        int pos = atomicAdd(&cur[p.x >> 16], 1);
        pairs[pos] = (p.x & 0xFFFFu) | ((unsigned int)f2bf(asfloat_u32(p.y)) << 16);
    }
}

// ---------------- GEMM, N=48(->40), K=128, MFMA, fully-staged A and B ----------------
// C[M x 40](bf16) = A[M x 128](bf16) @ Wt2^T ; Wt2 is [64][128] bf16, cols 40+ zero.
// Single barrier, no k-loop staging: A tile (64x128) and B (48x128) both fit LDS.
// LDP2=136 keeps bf16x8 stores 16B-aligned; read conflict structure == proven LDP=40.
#define LDP2 136
__global__ __launch_bounds__(256) void gemm_n48(const unsigned short* __restrict__ A,
                                                const unsigned short* __restrict__ Wt2,
                                                unsigned short* __restrict__ C, int M) {
    __shared__ unsigned short As[64 * LDP2];
    __shared__ unsigned short Bs[48 * LDP2];
    const int tid = threadIdx.x;
    const int wave = tid >> 6;
    const int lane = tid & 63;
    const int ln = lane & 15;
    const int quad = lane >> 4;
    const int row0 = blockIdx.x * 64;

#pragma unroll
    for (int i = 0; i < 4; ++i) {  // A: 64 rows x 128 = 1024 chunks of 8
        int q = tid + 256 * i;
        int r = q >> 4;
        int c = (q & 15) * 8;
        bf16x8 v;
        if (row0 + r < M) {
            v = *(const bf16x8*)(A + (size_t)(row0 + r) * 128 + c);
        } else {
#pragma unroll
            for (int j = 0; j < 8; ++j) v[j] = 0;
        }
        *(bf16x8*)&As[r * LDP2 + c] = v;
    }
#pragma unroll
    for (int i = 0; i < 3; ++i) {  // B: 48 rows x 128 = 768 chunks of 8
        int q = tid + 256 * i;
        int r = q >> 4;
        int c = (q & 15) * 8;
        *(bf16x8*)&Bs[r * LDP2 + c] = *(const bf16x8*)(Wt2 + (size_t)r * 128 + c);
    }
    __syncthreads();

    f32x4 acc[3];
#pragma unroll
    for (int t = 0; t < 3; ++t) acc[t] = (f32x4){0.f, 0.f, 0.f, 0.f};

#pragma unroll
    for (int kc = 0; kc < 128; kc += 32) {
        bf16x8 a = *(const bf16x8*)&As[(wave * 16 + ln) * LDP2 + kc + quad * 8];
#pragma unroll
        for (int t = 0; t < 3; ++t) {
            bf16x8 b = *(const bf16x8*)&Bs[(t * 16 + ln) * LDP2 + kc + quad * 8];
            acc[t] = __builtin_amdgcn_mfma_f32_16x16x32_bf16(a, b, acc[t], 0, 0, 0);
        }
    }

#pragma unroll
    for (int t = 0; t < 3; ++t) {
        int col = t * 16 + ln;
        if (col < NCLASS) {
#pragma unroll
            for (int r = 0; r < 4; ++r) {
                int row = row0 + wave * 16 + quad * 4 + r;
                if (row < M) C[(size_t)row * NCLASS + col] = f2bf(acc[t][r]);
            }
        }
    }
}

// ---------------- SpMM (CSR gather, bf16 rows) + bias + ReLU, feat=128 ----------------
// One wave per dst node, split into two 32-lane halves: half h gathers edge
// e+2i+h with uint2 (8B = 4 feats) per lane -> 16 edges in flight per wave,
// same 256B/row coalescing. Cross-half sums combined via __shfl_xor(.,32).
__global__ __launch_bounds__(256) void spmm_bias_relu_bf16(const unsigned short* __restrict__ t,
                                                           const int* __restrict__ row_ptr,
                                                           const unsigned int* __restrict__ pairs,
                                                           const float* __restrict__ bias,
                                                           unsigned short* __restrict__ out) {
    const int node = blockIdx.x * 4 + (threadIdx.x >> 6);
    const int lane = threadIdx.x & 63;
    const int half = lane >> 5;
    const int fq = (lane & 31) * 4;  // feature base (4 bf16 = 8B) owned by this lane
    const int e0 = row_ptr[node];
    const int e1 = row_ptr[node + 1];
    float a0 = 0.f, a1 = 0.f, a2 = 0.f, a3 = 0.f;
    int e = e0;
    for (; e + 16 <= e1; e += 16) {
        unsigned int p[8];
        uint2 v[8];
#pragma unroll
        for (int i = 0; i < 8; ++i) p[i] = pairs[e + 2 * i + half];
#pragma unroll
        for (int i = 0; i < 8; ++i)
            v[i] = *(const uint2*)(t + (size_t)(p[i] & 0xFFFFu) * 128 + fq);
#pragma unroll
        for (int i = 0; i < 8; ++i) {
            float w = asfloat_u32(p[i] & 0xFFFF0000u);
            a0 += w * asfloat_u32(v[i].x << 16);
            a1 += w * asfloat_u32(v[i].x & 0xFFFF0000u);
            a2 += w * asfloat_u32(v[i].y << 16);
            a3 += w * asfloat_u32(v[i].y & 0xFFFF0000u);
        }
    }
    for (; e + 2 <= e1; e += 2) {
        unsigned int p = pairs[e + half];
        uint2 v = *(const uint2*)(t + (size_t)(p & 0xFFFFu) * 128 + fq);
        float w = asfloat_u32(p & 0xFFFF0000u);
        a0 += w * asfloat_u32(v.x << 16);
        a1 += w * asfloat_u32(v.x & 0xFFFF0000u);
        a2 += w * asfloat_u32(v.y << 16);
        a3 += w * asfloat_u32(v.y & 0xFFFF0000u);
    }
    if (e < e1 && half == 0) {  // odd trailing edge: half 0 only
        unsigned int p = pairs[e];
        uint2 v = *(const uint2*)(t + (size_t)(p & 0xFFFFu) * 128 + fq);
        float w = asfloat_u32(p & 0xFFFF0000u);
        a0 += w * asfloat_u32(v.x << 16);
        a1 += w * asfloat_u32(v.x & 0xFFFF0000u);
        a2 += w * asfloat_u32(v.y << 16);
        a3 += w * asfloat_u32(v.y & 0xFFFF0000u);
    }
    a0 += __shfl_xor(a0, 32);
    a1 += __shfl_xor(a1, 32);
    a2 += __shfl_xor(a2, 32);
    a3 += __shfl_xor(a3, 32);
    if (half == 0) {
        float4 b = *(const float4*)&bias[fq];
        a0 = fmaxf(a0 + b.x, 0.f);
        a1 = fmaxf(a1 + b.y, 0.f);
        a2 = fmaxf(a2 + b.z, 0.f);
        a3 = fmaxf(a3 + b.w, 0.f);
        uint2 o;
        o.x = ((unsigned int)f2bf(a0)) | (((unsigned int)f2bf(a1)) << 16);
        o.y = ((unsigned int)f2bf(a2)) | (((unsigned int)f2bf(a3)) << 16);
        *(uint2*)(out + (size_t)node * 128 + fq) = o;
    }
}

// ---------------- SpMM feat=40 (bf16 rows) + bias + log_softmax ----------------
__global__ __launch_bounds__(256) void spmm_logsoftmax(const unsigned short* __restrict__ t,
                                                       const int* __restrict__ row_ptr,
                                                       const unsigned int* __restrict__ pairs,
                                                       const float* __restrict__ bias,
                                                       float* __restrict__ out) {
    const int node = blockIdx.x * 4 + (threadIdx.x >> 6);
    const int lane = threadIdx.x & 63;
    const int e0 = row_ptr[node];
    const int e1 = row_ptr[node + 1];
    const bool act = lane < NCLASS;
    float acc = 0.f;
    int e = e0;
    for (; e + 8 <= e1; e += 8) {
        unsigned int p[8];
#pragma unroll
        for (int i = 0; i < 8; ++i) p[i] = pairs[e + i];
        if (act) {
            float v[8];
#pragma unroll
            for (int i = 0; i < 8; ++i)
                v[i] = asfloat_u32((unsigned int)t[(size_t)(p[i] & 0xFFFFu) * NCLASS + lane] << 16);
#pragma unroll
            for (int i = 0; i < 8; ++i) acc += asfloat_u32(p[i] & 0xFFFF0000u) * v[i];
        }
    }
    for (; e < e1; ++e) {
        unsigned int p = pairs[e];
        if (act)
            acc += asfloat_u32(p & 0xFFFF0000u) *
                   asfloat_u32((unsigned int)t[(size_t)(p & 0xFFFFu) * NCLASS + lane] << 16);
    }
    float logit = act ? (acc + bias[lane]) : -INFINITY;
    float m = logit;
#pragma unroll
    for (int off = 32; off; off >>= 1) m = fmaxf(m, __shfl_xor(m, off));
    float ex = act ? __expf(logit - m) : 0.f;
    float ssum = ex;
#pragma unroll
    for (int off = 32; off; off >>= 1) ssum += __shfl_xor(ssum, off);
    if (act) out[(size_t)node * NCLASS + lane] = logit - m - __logf(ssum);
}

// ---------------- launch ----------------

extern "C" void kernel_launch(void* const* d_in, const int* in_sizes, int n_in,
                              void* d_out, int out_size, void* d_ws, size_t ws_size,
                              hipStream_t stream) {
    const float* x = (const float*)d_in[0];
    const int* edge_src = (const int*)d_in[1];
    const int* edge_dst = (const int*)d_in[2];
    const float* edge_weight = (const float*)d_in[3];
    const float* W1 = (const float*)d_in[4];
    const float* b1 = (const float*)d_in[5];
    const float* Wh = (const float*)d_in[6];
    const float* bh = (const float*)d_in[7];
    const float* W2 = (const float*)d_in[8];
    const float* b2 = (const float*)d_in[9];
    float* out = (float*)d_out;

    size_t off = 0;
    auto carve = [&](size_t bytes) {
        void* p = (char*)d_ws + off;
        off += (bytes + 511) & ~(size_t)511;
        return p;
    };
    unsigned short* tb = (unsigned short*)carve((size_t)N_NODES * 128 * 2);
    unsigned short* hb = (unsigned short*)carve((size_t)N_NODES * 128 * 2);
    unsigned short* t3 = (unsigned short*)carve((size_t)N_NODES * NCLASS * 2);
    unsigned short* Wt1 = (unsigned short*)carve((size_t)NFEAT * NHID * 2);
    unsigned short* Wth = (unsigned short*)carve((size_t)NHID * NHID * 2);
    unsigned short* Wt2 = (unsigned short*)carve((size_t)64 * NHID * 2);
    int* row_ptr = (int*)carve((size_t)(N_NODES + 4) * 4);
    int* bucketCursor = (int*)carve((size_t)NBUCKETS * 4);
    uint2* binned = (uint2*)carve((size_t)NBUCKETS * BUCKET_CAP * 8);
    unsigned int* pairs = (unsigned int*)carve((size_t)N_EDGES * 4);
    (void)ws_size; (void)n_in; (void)in_sizes; (void)out_size;

    const int prepBlocks =
        (NFEAT * NHID + NHID * NHID + 64 * NHID + NBUCKETS + 255) / 256;  // 353
    const int spmmBlocks = N_NODES / 4;            // 12500
    const int gemmBlocks = (N_NODES + 63) / 64;    // 782

    // prep (weights + cursors)
    prep_kernel<<<prepBlocks, 256, 0, stream>>>(W1, Wt1, Wh, Wth, W2, Wt2, bucketCursor);

    // GEMM1 || bin (independent work fused into one launch)
    fused_gemm1_bin<<<GEMM1_BLOCKS + BIN_BLOCKS, 256, 0, stream>>>(
        x, Wt1, tb, edge_src, edge_dst, edge_weight, bucketCursor, binned);

    // CSR finalize (inline bucket scan; 1024 thr -- 196 blocks are latency-critical)
    build_csr<<<NBUCKETS, 1024, 0, stream>>>(binned, bucketCursor, pairs, row_ptr);

    // Layer 1 aggregate
    spmm_bias_relu_bf16<<<spmmBlocks, 256, 0, stream>>>(tb, row_ptr, pairs, b1, hb);

    // Layer 2
    gemm64_l2<<<gemmBlocks, 256, 0, stream>>>(hb, Wth, tb);
    spmm_bias_relu_bf16<<<spmmBlocks, 256, 0, stream>>>(tb, row_ptr, pairs, bh, hb);

    // Layer 3 (MFMA, fully-staged tiles)
    gemm_n48<<<gemmBlocks, 256, 0, stream>>>(hb, Wt2, t3, N_NODES);
    spmm_logsoftmax<<<spmmBlocks, 256, 0, stream>>>(t3, row_ptr, pairs, b2, out);
}

// Round 3
// 389.650 us; speedup vs baseline: 1.1217x; 1.0175x over previous
//
#include <hip/hip_runtime.h>
#include <hip/hip_bf16.h>
#include <math.h>

#define N_NODES 50000
#define N_EDGES 1600000
#define NFEAT 512
#define NHID 128
#define NCLASS 40

#define NBUCKETS 196      // ceil(N_NODES / 256), dst>>8
#define BUCKET_CAP 16384  // avg fill ~8163 -> huge margin

typedef __attribute__((ext_vector_type(8))) short bf16x8;
typedef __attribute__((ext_vector_type(4))) float f32x4;

static __device__ __forceinline__ float asfloat_u32(unsigned int u) {
    union { unsigned int u; float f; } c;
    c.u = u;
    return c.f;
}
static __device__ __forceinline__ unsigned int asu32_f(float f) {
    union { float f; unsigned int u; } c;
    c.f = f;
    return c.u;
}
static __device__ __forceinline__ unsigned short f2bf(float f) {
    union { float f; unsigned int u; } c;
    c.f = f;
    unsigned int r = c.u + 0x7FFFu + ((c.u >> 16) & 1u);  // RTN-even
    return (unsigned short)(r >> 16);
}

// ---------------- prep: bucket cursors + weight transposes (W1, Wh, W2) ----------------
// Wt2 is [64][128] bf16: Wt2[n][k] = W2[k][n] for n<40, 0 for 40<=n<64 (MFMA col padding).
__global__ __launch_bounds__(256) void prep_kernel(const float* __restrict__ W1,
                                                   unsigned short* __restrict__ Wt1,
                                                   const float* __restrict__ Wh,
                                                   unsigned short* __restrict__ Wth,
                                                   const float* __restrict__ W2,
                                                   unsigned short* __restrict__ Wt2,
                                                   int* __restrict__ bucketCursor) {
    int idx = blockIdx.x * 256 + threadIdx.x;
    if (idx < NFEAT * NHID) {  // Wt1[n][k] = bf16(W1[k][n])
        int k = idx >> 7;
        int n = idx & 127;
        Wt1[(size_t)n * NFEAT + k] = f2bf(W1[idx]);
    } else if (idx < NFEAT * NHID + NHID * NHID) {
        int j = idx - NFEAT * NHID;
        int k = j >> 7;
        int n = j & 127;
        Wth[(size_t)n * NHID + k] = f2bf(Wh[j]);
    } else if (idx < NFEAT * NHID + NHID * NHID + 64 * NHID) {
        int j = idx - (NFEAT * NHID + NHID * NHID);
        int n = j & 63;
        int k = j >> 6;
        Wt2[(size_t)n * NHID + k] = (n < NCLASS) ? f2bf(W2[(size_t)k * NCLASS + n]) : 0;
    } else {
        int j = idx - (NFEAT * NHID + NHID * NHID + 64 * NHID);
        if (j < NBUCKETS) bucketCursor[j] = j * BUCKET_CAP;
    }
}

// ---------------- GEMM (64-row tile) body, N=128, BK=64 ----------------
// C[M x 128](bf16) = A[M x K] @ Wt^T ; Wt is [128][K] bf16.
// 256 thr / 4 waves; wave w covers rows [w*16, w*16+16); 8 col MFMA tiles.
// BK=64 per barrier pair: 16 MFMAs/barrier, half the latency phases of BK=32.
// (r1 lesson: register depth-2 prefetch REGRESSED -- barriers lockstep waves;
//  the win is fewer/fatter phases, not deeper register pipelines.)
// LDS rows padded to LDPA=72 bf16 (144B stride -> 2-way bank aliasing = free).
#define LDPA 72
#define GEMM_LDS_BYTES ((64 + 128) * LDPA * 2)  // 27648 B -> 5 blocks/CU by LDS

template <bool A_IS_BF16>
static __device__ __forceinline__ void gemm64_body(const void* __restrict__ Ap,
                                                   const unsigned short* __restrict__ Wt,
                                                   unsigned short* __restrict__ C,
                                                   const int M, const int K,
                                                   char* smem, int bid) {
    unsigned short* As = (unsigned short*)smem;              // 64 x LDPA
    unsigned short* Bs = (unsigned short*)smem + 64 * LDPA;  // 128 x LDPA
    const int tid = threadIdx.x;
    const int wave = tid >> 6;
    const int lane = tid & 63;
    const int ln = lane & 15;
    const int quad = lane >> 4;
    const int row0 = bid * 64;

    const int ar = tid >> 2;         // A staging row 0..63
    const int ac = (tid & 3) * 16;   // A staging k-offset (16 elems = 2x bf16x8)
    const bool arOk = (row0 + ar) < M;
    const int bn = tid >> 1;         // B staging col(n) 0..127
    const int bk = (tid & 1) * 32;   // B staging k-offset (32 elems = 4x bf16x8)

    f32x4 acc[8];
#pragma unroll
    for (int t = 0; t < 8; ++t) acc[t] = (f32x4){0.f, 0.f, 0.f, 0.f};

    for (int kc = 0; kc < K; kc += 64) {
        bf16x8 va0, va1;
        if (A_IS_BF16) {
            if (arOk) {
                const unsigned short* Ab =
                    (const unsigned short*)Ap + (size_t)(row0 + ar) * K + kc + ac;
                va0 = *(const bf16x8*)Ab;
                va1 = *(const bf16x8*)(Ab + 8);
            } else {
#pragma unroll
                for (int i = 0; i < 8; ++i) { va0[i] = 0; va1[i] = 0; }
            }
        } else {
            if (arOk) {
                const float* Af = (const float*)Ap + (size_t)(row0 + ar) * K + kc + ac;
                float4 f0 = *(const float4*)(Af);
                float4 f1 = *(const float4*)(Af + 4);
                float4 f2 = *(const float4*)(Af + 8);
                float4 f3 = *(const float4*)(Af + 12);
                va0[0] = (short)f2bf(f0.x); va0[1] = (short)f2bf(f0.y);
                va0[2] = (short)f2bf(f0.z); va0[3] = (short)f2bf(f0.w);
                va0[4] = (short)f2bf(f1.x); va0[5] = (short)f2bf(f1.y);
                va0[6] = (short)f2bf(f1.z); va0[7] = (short)f2bf(f1.w);
                va1[0] = (short)f2bf(f2.x); va1[1] = (short)f2bf(f2.y);
                va1[2] = (short)f2bf(f2.z); va1[3] = (short)f2bf(f2.w);
                va1[4] = (short)f2bf(f3.x); va1[5] = (short)f2bf(f3.y);
                va1[6] = (short)f2bf(f3.z); va1[7] = (short)f2bf(f3.w);
            } else {
#pragma unroll
                for (int i = 0; i < 8; ++i) { va0[i] = 0; va1[i] = 0; }
            }
        }
        const unsigned short* Bg = Wt + (size_t)bn * K + kc + bk;
        bf16x8 vb0 = *(const bf16x8*)(Bg);
        bf16x8 vb1 = *(const bf16x8*)(Bg + 8);
        bf16x8 vb2 = *(const bf16x8*)(Bg + 16);
        bf16x8 vb3 = *(const bf16x8*)(Bg + 24);

        __syncthreads();  // previous iteration's LDS reads done
        *(bf16x8*)&As[ar * LDPA + ac] = va0;
        *(bf16x8*)&As[ar * LDPA + ac + 8] = va1;
        *(bf16x8*)&Bs[bn * LDPA + bk] = vb0;
        *(bf16x8*)&Bs[bn * LDPA + bk + 8] = vb1;
        *(bf16x8*)&Bs[bn * LDPA + bk + 16] = vb2;
        *(bf16x8*)&Bs[bn * LDPA + bk + 24] = vb3;
        __syncthreads();

        bf16x8 a0 = *(const bf16x8*)&As[(wave * 16 + ln) * LDPA + quad * 8];
        bf16x8 a1 = *(const bf16x8*)&As[(wave * 16 + ln) * LDPA + 32 + quad * 8];
#pragma unroll
        for (int t = 0; t < 8; ++t) {
            bf16x8 b0 = *(const bf16x8*)&Bs[(t * 16 + ln) * LDPA + quad * 8];
            acc[t] = __builtin_amdgcn_mfma_f32_16x16x32_bf16(a0, b0, acc[t], 0, 0, 0);
        }
#pragma unroll
        for (int t = 0; t < 8; ++t) {
            bf16x8 b1 = *(const bf16x8*)&Bs[(t * 16 + ln) * LDPA + 32 + quad * 8];
            acc[t] = __builtin_amdgcn_mfma_f32_16x16x32_bf16(a1, b1, acc[t], 0, 0, 0);
        }
    }

#pragma unroll
    for (int t = 0; t < 8; ++t) {
#pragma unroll
        for (int r = 0; r < 4; ++r) {
            int row = row0 + wave * 16 + quad * 4 + r;
            if (row < M) C[(size_t)row * 128 + t * 16 + ln] = f2bf(acc[t][r]);
        }
    }
}

// ---------------- bin body: bucket edges by dst>>8 ----------------
// Record: x = src | (dstLow8)<<16 ; y = fp32 weight bits.
static __device__ __forceinline__ void bin_body(const int* __restrict__ src,
                                                const int* __restrict__ dst,
                                                const float* __restrict__ w,
                                                int* __restrict__ bucketCursor,
                                                uint2* __restrict__ binned,
                                                int n, char* smem, int bid) {
    int* hist = (int*)smem;            // NBUCKETS
    int* cur = (int*)smem + NBUCKETS;  // NBUCKETS
    const int tid = threadIdx.x;
    const int base = bid * 4096;
    if (tid < NBUCKETS) hist[tid] = 0;
    __syncthreads();
#pragma unroll
    for (int r = 0; r < 16; ++r) {
        int e = base + r * 256 + tid;
        if (e < n) atomicAdd(&hist[dst[e] >> 8], 1);
    }
    __syncthreads();
    if (tid < NBUCKETS && hist[tid] > 0)
        cur[tid] = atomicAdd(&bucketCursor[tid], hist[tid]);
    __syncthreads();
#pragma unroll
    for (int r = 0; r < 16; ++r) {
        int e = base + r * 256 + tid;
        if (e < n) {
            int d = dst[e];
            int pos = atomicAdd(&cur[d >> 8], 1);
            uint2 rec;
            rec.x = (unsigned int)src[e] | ((unsigned int)(d & 255) << 16);
            rec.y = asu32_f(w[e]);
            binned[pos] = rec;
        }
    }
}

// ---------------- fused: GEMM1 (782 blocks) || bin (391 blocks) ----------------
#define GEMM1_BLOCKS 782
#define BIN_BLOCKS 391
__global__ __launch_bounds__(256) void fused_gemm1_bin(const float* __restrict__ x,
                                                       const unsigned short* __restrict__ Wt1,
                                                       unsigned short* __restrict__ tb,
                                                       const int* __restrict__ src,
                                                       const int* __restrict__ dst,
                                                       const float* __restrict__ w,
                                                       int* __restrict__ bucketCursor,
                                                       uint2* __restrict__ binned) {
    __shared__ char smem[GEMM_LDS_BYTES];
    if (blockIdx.x < GEMM1_BLOCKS) {
        gemm64_body<false>(x, Wt1, tb, N_NODES, NFEAT, smem, blockIdx.x);
    } else {
        bin_body(src, dst, w, bucketCursor, binned, N_EDGES, smem,
                 blockIdx.x - GEMM1_BLOCKS);
    }
}

// ---------------- standalone GEMM layer 2 ----------------
__global__ __launch_bounds__(256) void gemm64_l2(const unsigned short* __restrict__ A,
                                                 const unsigned short* __restrict__ Wt,
                                                 unsigned short* __restrict__ C) {
    __shared__ char smem[GEMM_LDS_BYTES];
    gemm64_body<true>(A, Wt, C, N_NODES, NHID, smem, blockIdx.x);
}

// ---------------- build_csr (inline bucket scan): 4B edge records ----------------
// pairs[pos] = src(16b) | bf16(weight)(16b high)
// 1024 threads/block: 196 blocks = 0.77 blocks/CU, so per-block latency IS the
// kernel duration -- 4x threads = 4x fewer serial iterations per block.
__global__ __launch_bounds__(1024) void build_csr(const uint2* __restrict__ binned,
                                                  const int* __restrict__ bucketCursor,
                                                  unsigned int* __restrict__ pairs,
                                                  int* __restrict__ row_ptr) {
    __shared__ int bs[256];
    __shared__ int hist[256];
    __shared__ int sc[256];
    __shared__ int cur[256];
    const int b = blockIdx.x;
    const int tid = threadIdx.x;

    // inline exclusive scan of bucket fills (tid<256 participate; all sync)
    if (tid < 256) bs[tid] = (tid < NBUCKETS) ? (bucketCursor[tid] - tid * BUCKET_CAP) : 0;
    if (tid < 256) hist[tid] = 0;
    __syncthreads();
    for (int off = 1; off < 256; off <<= 1) {
        int t = 0;
        if (tid < 256 && tid >= off) t = bs[tid - off];
        __syncthreads();
        if (tid < 256) bs[tid] += t;
        __syncthreads();
    }
    const int cnt = bucketCursor[b] - b * BUCKET_CAP;
    const int segStart = bs[b] - cnt;  // exclusive prefix at b
    if (b == NBUCKETS - 1 && tid == 0) row_ptr[N_NODES] = bs[NBUCKETS - 1];
    const uint2* seg = binned + (size_t)b * BUCKET_CAP;

    for (int i = tid; i < cnt; i += 1024)
        atomicAdd(&hist[seg[i].x >> 16], 1);
    __syncthreads();
    if (tid < 256) {
        int v = hist[tid];
        sc[tid] = v;
    }
    __syncthreads();
    for (int off = 1; off < 256; off <<= 1) {
        int t = 0;
        if (tid < 256 && tid >= off) t = sc[tid - off];
        __syncthreads();
        if (tid < 256) sc[tid] += t;
        __syncthreads();
    }
    if (tid < 256) {
        int excl = sc[tid] - hist[tid];
        int node = b * 256 + tid;
        if (node < N_NODES) row_ptr[node] = segStart + excl;
        cur[tid] = segStart + excl;
    }
    __syncthreads();
    for (int i = tid; i < cnt; i += 1024) {
        uint2 p = seg[i];
        int pos = atomicAdd(&cur[p.x >> 16], 1);
        pairs[pos] = (p.x & 0xFFFFu) | ((unsigned int)f2bf(asfloat_u32(p.y)) << 16);
    }
}

// ---------------- GEMM, N=48(->40), K=128, MFMA, fully-staged A and B ----------------
// C[M x 40](bf16) = A[M x 128](bf16) @ Wt2^T ; Wt2 is [64][128] bf16, cols 40+ zero.
// Single barrier, no k-loop staging: A tile (64x128) and B (48x128) both fit LDS.
#define LDP2 136
__global__ __launch_bounds__(256) void gemm_n48(const unsigned short* __restrict__ A,
                                                const unsigned short* __restrict__ Wt2,
                                                unsigned short* __restrict__ C, int M) {
    __shared__ unsigned short As[64 * LDP2];
    __shared__ unsigned short Bs[48 * LDP2];
    const int tid = threadIdx.x;
    const int wave = tid >> 6;
    const int lane = tid & 63;
    const int ln = lane & 15;
    const int quad = lane >> 4;
    const int row0 = blockIdx.x * 64;

#pragma unroll
    for (int i = 0; i < 4; ++i) {  // A: 64 rows x 128 = 1024 chunks of 8
        int q = tid + 256 * i;
        int r = q >> 4;
        int c = (q & 15) * 8;
        bf16x8 v;
        if (row0 + r < M) {
            v = *(const bf16x8*)(A + (size_t)(row0 + r) * 128 + c);
        } else {
#pragma unroll
            for (int j = 0; j < 8; ++j) v[j] = 0;
        }
        *(bf16x8*)&As[r * LDP2 + c] = v;
    }
#pragma unroll
    for (int i = 0; i < 3; ++i) {  // B: 48 rows x 128 = 768 chunks of 8
        int q = tid + 256 * i;
        int r = q >> 4;
        int c = (q & 15) * 8;
        *(bf16x8*)&Bs[r * LDP2 + c] = *(const bf16x8*)(Wt2 + (size_t)r * 128 + c);
    }
    __syncthreads();

    f32x4 acc[3];
#pragma unroll
    for (int t = 0; t < 3; ++t) acc[t] = (f32x4){0.f, 0.f, 0.f, 0.f};

#pragma unroll
    for (int kc = 0; kc < 128; kc += 32) {
        bf16x8 a = *(const bf16x8*)&As[(wave * 16 + ln) * LDP2 + kc + quad * 8];
#pragma unroll
        for (int t = 0; t < 3; ++t) {
            bf16x8 b = *(const bf16x8*)&Bs[(t * 16 + ln) * LDP2 + kc + quad * 8];
            acc[t] = __builtin_amdgcn_mfma_f32_16x16x32_bf16(a, b, acc[t], 0, 0, 0);
        }
    }

#pragma unroll
    for (int t = 0; t < 3; ++t) {
        int col = t * 16 + ln;
        if (col < NCLASS) {
#pragma unroll
            for (int r = 0; r < 4; ++r) {
                int row = row0 + wave * 16 + quad * 4 + r;
                if (row < M) C[(size_t)row * NCLASS + col] = f2bf(acc[t][r]);
            }
        }
    }
}

// ---------------- SpMM (CSR gather, bf16 rows) + bias + ReLU, feat=128 ----------------
// One wave per dst node, split into FOUR 16-lane groups: group g gathers edge
// e+4i+g with a full 256B row (16 lanes x 16B bf16x8) -> 4 edges/instruction,
// unroll 8 -> 32 edges in flight per wave (2x the r1 version). Cross-group
// sums combined via __shfl_xor(16) + __shfl_xor(32); group 0 writes 16B/lane.
__global__ __launch_bounds__(256) void spmm_bias_relu_bf16(const unsigned short* __restrict__ t,
                                                           const int* __restrict__ row_ptr,
                                                           const unsigned int* __restrict__ pairs,
                                                           const float* __restrict__ bias,
                                                           unsigned short* __restrict__ out) {
    const int node = blockIdx.x * 4 + (threadIdx.x >> 6);
    const int lane = threadIdx.x & 63;
    const int g = lane >> 4;        // group 0..3
    const int fl = (lane & 15) * 8; // feature base: 8 bf16 = 16B owned by this lane
    const int e0 = row_ptr[node];
    const int e1 = row_ptr[node + 1];
    float acc8[8];
#pragma unroll
    for (int j = 0; j < 8; ++j) acc8[j] = 0.f;

    int e = e0;
    for (; e + 32 <= e1; e += 32) {
        unsigned int p[8];
        uint4 v[8];
#pragma unroll
        for (int i = 0; i < 8; ++i) p[i] = pairs[e + 4 * i + g];
#pragma unroll
        for (int i = 0; i < 8; ++i)
            v[i] = *(const uint4*)(t + (size_t)(p[i] & 0xFFFFu) * 128 + fl);
#pragma unroll
        for (int i = 0; i < 8; ++i) {
            float w = asfloat_u32(p[i] & 0xFFFF0000u);
            acc8[0] += w * asfloat_u32(v[i].x << 16);
            acc8[1] += w * asfloat_u32(v[i].x & 0xFFFF0000u);
            acc8[2] += w * asfloat_u32(v[i].y << 16);
            acc8[3] += w * asfloat_u32(v[i].y & 0xFFFF0000u);
            acc8[4] += w * asfloat_u32(v[i].z << 16);
            acc8[5] += w * asfloat_u32(v[i].z & 0xFFFF0000u);
            acc8[6] += w * asfloat_u32(v[i].w << 16);
            acc8[7] += w * asfloat_u32(v[i].w & 0xFFFF0000u);
        }
    }
    for (; e + 4 <= e1; e += 4) {
        unsigned int p = pairs[e + g];
        uint4 v = *(const uint4*)(t + (size_t)(p & 0xFFFFu) * 128 + fl);
        float w = asfloat_u32(p & 0xFFFF0000u);
        acc8[0] += w * asfloat_u32(v.x << 16);
        acc8[1] += w * asfloat_u32(v.x & 0xFFFF0000u);
        acc8[2] += w * asfloat_u32(v.y << 16);
        acc8[3] += w * asfloat_u32(v.y & 0xFFFF0000u);
        acc8[4] += w * asfloat_u32(v.z << 16);
        acc8[5] += w * asfloat_u32(v.z & 0xFFFF0000u);
        acc8[6] += w * asfloat_u32(v.w << 16);
        acc8[7] += w * asfloat_u32(v.w & 0xFFFF0000u);
    }
    if (g < e1 - e) {  // remainder 0..3 edges, one per group
        unsigned int p = pairs[e + g];
        uint4 v = *(const uint4*)(t + (size_t)(p & 0xFFFFu) * 128 + fl);
        float w = asfloat_u32(p & 0xFFFF0000u);
        acc8[0] += w * asfloat_u32(v.x << 16);
        acc8[1] += w * asfloat_u32(v.x & 0xFFFF0000u);
        acc8[2] += w * asfloat_u32(v.y << 16);
        acc8[3] += w * asfloat_u32(v.y & 0xFFFF0000u);
        acc8[4] += w * asfloat_u32(v.z << 16);
        acc8[5] += w * asfloat_u32(v.z & 0xFFFF0000u);
        acc8[6] += w * asfloat_u32(v.w << 16);
        acc8[7] += w * asfloat_u32(v.w & 0xFFFF0000u);
    }
    // lanes l, l^16, l^32, l^48 own the same 8 features -> butterfly over groups
#pragma unroll
    for (int j = 0; j < 8; ++j) {
        acc8[j] += __shfl_xor(acc8[j], 16);
        acc8[j] += __shfl_xor(acc8[j], 32);
    }
    if (g == 0) {
        float4 b0 = *(const float4*)&bias[fl];
        float4 b1 = *(const float4*)&bias[fl + 4];
        acc8[0] = fmaxf(acc8[0] + b0.x, 0.f);
        acc8[1] = fmaxf(acc8[1] + b0.y, 0.f);
        acc8[2] = fmaxf(acc8[2] + b0.z, 0.f);
        acc8[3] = fmaxf(acc8[3] + b0.w, 0.f);
        acc8[4] = fmaxf(acc8[4] + b1.x, 0.f);
        acc8[5] = fmaxf(acc8[5] + b1.y, 0.f);
        acc8[6] = fmaxf(acc8[6] + b1.z, 0.f);
        acc8[7] = fmaxf(acc8[7] + b1.w, 0.f);
        uint4 o;
        o.x = ((unsigned int)f2bf(acc8[0])) | (((unsigned int)f2bf(acc8[1])) << 16);
        o.y = ((unsigned int)f2bf(acc8[2])) | (((unsigned int)f2bf(acc8[3])) << 16);
        o.z = ((unsigned int)f2bf(acc8[4])) | (((unsigned int)f2bf(acc8[5])) << 16);
        o.w = ((unsigned int)f2bf(acc8[6])) | (((unsigned int)f2bf(acc8[7])) << 16);
        *(uint4*)(out + (size_t)node * 128 + fl) = o;
    }
}

// ---------------- SpMM feat=40 (bf16 rows) + bias + log_softmax ----------------
__global__ __launch_bounds__(256) void spmm_logsoftmax(const unsigned short* __restrict__ t,
                                                       const int* __restrict__ row_ptr,
                                                       const unsigned int* __restrict__ pairs,
                                                       const float* __restrict__ bias,
                                                       float* __restrict__ out) {
    const int node = blockIdx.x * 4 + (threadIdx.x >> 6);
    const int lane = threadIdx.x & 63;
    const int e0 = row_ptr[node];
    const int e1 = row_ptr[node + 1];
    const bool act = lane < NCLASS;
    float acc = 0.f;
    int e = e0;
    for (; e + 8 <= e1; e += 8) {
        unsigned int p[8];
#pragma unroll
        for (int i = 0; i < 8; ++i) p[i] = pairs[e + i];
        if (act) {
            float v[8];
#pragma unroll
            for (int i = 0; i < 8; ++i)
                v[i] = asfloat_u32((unsigned int)t[(size_t)(p[i] & 0xFFFFu) * NCLASS + lane] << 16);
#pragma unroll
            for (int i = 0; i < 8; ++i) acc += asfloat_u32(p[i] & 0xFFFF0000u) * v[i];
        }
    }
    for (; e < e1; ++e) {
        unsigned int p = pairs[e];
        if (act)
            acc += asfloat_u32(p & 0xFFFF0000u) *
                   asfloat_u32((unsigned int)t[(size_t)(p & 0xFFFFu) * NCLASS + lane] << 16);
    }
    float logit = act ? (acc + bias[lane]) : -INFINITY;
    float m = logit;
#pragma unroll
    for (int off = 32; off; off >>= 1) m = fmaxf(m, __shfl_xor(m, off));
    float ex = act ? __expf(logit - m) : 0.f;
    float ssum = ex;
#pragma unroll
    for (int off = 32; off; off >>= 1) ssum += __shfl_xor(ssum, off);
    if (act) out[(size_t)node * NCLASS + lane] = logit - m - __logf(ssum);
}

// ---------------- launch ----------------

extern "C" void kernel_launch(void* const* d_in, const int* in_sizes, int n_in,
                              void* d_out, int out_size, void* d_ws, size_t ws_size,
                              hipStream_t stream) {
    const float* x = (const float*)d_in[0];
    const int* edge_src = (const int*)d_in[1];
    const int* edge_dst = (const int*)d_in[2];
    const float* edge_weight = (const float*)d_in[3];
    const float* W1 = (const float*)d_in[4];
    const float* b1 = (const float*)d_in[5];
    const float* Wh = (const float*)d_in[6];
    const float* bh = (const float*)d_in[7];
    const float* W2 = (const float*)d_in[8];
    const float* b2 = (const float*)d_in[9];
    float* out = (float*)d_out;

    size_t off = 0;
    auto carve = [&](size_t bytes) {
        void* p = (char*)d_ws + off;
        off += (bytes + 511) & ~(size_t)511;
        return p;
    };
    unsigned short* tb = (unsigned short*)carve((size_t)N_NODES * 128 * 2);
    unsigned short* hb = (unsigned short*)carve((size_t)N_NODES * 128 * 2);
    unsigned short* t3 = (unsigned short*)carve((size_t)N_NODES * NCLASS * 2);
    unsigned short* Wt1 = (unsigned short*)carve((size_t)NFEAT * NHID * 2);
    unsigned short* Wth = (unsigned short*)carve((size_t)NHID * NHID * 2);
    unsigned short* Wt2 = (unsigned short*)carve((size_t)64 * NHID * 2);
    int* row_ptr = (int*)carve((size_t)(N_NODES + 4) * 4);
    int* bucketCursor = (int*)carve((size_t)NBUCKETS * 4);
    uint2* binned = (uint2*)carve((size_t)NBUCKETS * BUCKET_CAP * 8);
    unsigned int* pairs = (unsigned int*)carve((size_t)N_EDGES * 4);
    (void)ws_size; (void)n_in; (void)in_sizes; (void)out_size;

    const int prepBlocks =
        (NFEAT * NHID + NHID * NHID + 64 * NHID + NBUCKETS + 255) / 256;  // 353
    const int spmmBlocks = N_NODES / 4;            // 12500
    const int gemmBlocks = (N_NODES + 63) / 64;    // 782

    // prep (weights + cursors)
    prep_kernel<<<prepBlocks, 256, 0, stream>>>(W1, Wt1, Wh, Wth, W2, Wt2, bucketCursor);

    // GEMM1 || bin (independent work fused into one launch)
    fused_gemm1_bin<<<GEMM1_BLOCKS + BIN_BLOCKS, 256, 0, stream>>>(
        x, Wt1, tb, edge_src, edge_dst, edge_weight, bucketCursor, binned);

    // CSR finalize (inline bucket scan; 1024 thr -- 196 blocks are latency-critical)
    build_csr<<<NBUCKETS, 1024, 0, stream>>>(binned, bucketCursor, pairs, row_ptr);

    // Layer 1 aggregate
    spmm_bias_relu_bf16<<<spmmBlocks, 256, 0, stream>>>(tb, row_ptr, pairs, b1, hb);

    // Layer 2
    gemm64_l2<<<gemmBlocks, 256, 0, stream>>>(hb, Wth, tb);
    spmm_bias_relu_bf16<<<spmmBlocks, 256, 0, stream>>>(tb, row_ptr, pairs, bh, hb);

    // Layer 3 (MFMA, fully-staged tiles)
    gemm_n48<<<gemmBlocks, 256, 0, stream>>>(hb, Wt2, t3, N_NODES);
    spmm_logsoftmax<<<spmmBlocks, 256, 0, stream>>>(t3, row_ptr, pairs, b2, out);
}

// Round 4
// 386.361 us; speedup vs baseline: 1.1313x; 1.0085x over previous
//
#include <hip/hip_runtime.h>
#include <hip/hip_bf16.h>
#include <math.h>

#define N_NODES 50000
#define N_EDGES 1600000
#define NFEAT 512
#define NHID 128
#define NCLASS 40

#define NBUCKETS 196      // ceil(N_NODES / 256), dst>>8
#define BUCKET_CAP 16384  // avg fill ~8163 -> huge margin

typedef __attribute__((ext_vector_type(8))) short bf16x8;
typedef __attribute__((ext_vector_type(4))) float f32x4;

static __device__ __forceinline__ float asfloat_u32(unsigned int u) {
    union { unsigned int u; float f; } c;
    c.u = u;
    return c.f;
}
static __device__ __forceinline__ unsigned int asu32_f(float f) {
    union { float f; unsigned int u; } c;
    c.f = f;
    return c.u;
}
static __device__ __forceinline__ unsigned short f2bf(float f) {
    union { float f; unsigned int u; } c;
    c.f = f;
    unsigned int r = c.u + 0x7FFFu + ((c.u >> 16) & 1u);  // RTN-even
    return (unsigned short)(r >> 16);
}

// ---------------- prep: bucket cursors + weight transposes (W1, Wh, W2) ----------------
// Wt2 is [64][128] bf16: Wt2[n][k] = W2[k][n] for n<40, 0 for 40<=n<64 (MFMA col padding).
__global__ __launch_bounds__(256) void prep_kernel(const float* __restrict__ W1,
                                                   unsigned short* __restrict__ Wt1,
                                                   const float* __restrict__ Wh,
                                                   unsigned short* __restrict__ Wth,
                                                   const float* __restrict__ W2,
                                                   unsigned short* __restrict__ Wt2,
                                                   int* __restrict__ bucketCursor) {
    int idx = blockIdx.x * 256 + threadIdx.x;
    if (idx < NFEAT * NHID) {  // Wt1[n][k] = bf16(W1[k][n])
        int k = idx >> 7;
        int n = idx & 127;
        Wt1[(size_t)n * NFEAT + k] = f2bf(W1[idx]);
    } else if (idx < NFEAT * NHID + NHID * NHID) {
        int j = idx - NFEAT * NHID;
        int k = j >> 7;
        int n = j & 127;
        Wth[(size_t)n * NHID + k] = f2bf(Wh[j]);
    } else if (idx < NFEAT * NHID + NHID * NHID + 64 * NHID) {
        int j = idx - (NFEAT * NHID + NHID * NHID);
        int n = j & 63;
        int k = j >> 6;
        Wt2[(size_t)n * NHID + k] = (n < NCLASS) ? f2bf(W2[(size_t)k * NCLASS + n]) : 0;
    } else {
        int j = idx - (NFEAT * NHID + NHID * NHID + 64 * NHID);
        if (j < NBUCKETS) bucketCursor[j] = j * BUCKET_CAP;
    }
}

// ---------------- GEMM (64-row tile) body, N=128, BK=64, A-direct ----------------
// C[M x 128](bf16) = A[M x K] @ Wt^T ; Wt is [128][K] bf16.
// KEY CHANGE (r4): the MFMA A-fragment is per-lane-exclusive (lane owns row
// wave*16+ln, k-slice quad*8), so A goes global->register DIRECTLY -- no LDS
// staging, no A barrier dependency. LDS holds only B, double-buffered ->
// ONE barrier per k-step. LDS traffic halved, barrier count halved.
// (r1 lesson: reg prefetch with LDS both-staging regressed; this removes the
//  staging instead of deepening the pipeline.)
#define LDPB 72  // B row pitch in bf16 (144B; measured-ok conflict level in r3)
#define GEMM_LDS_BYTES (2 * 128 * LDPB * 2)  // 36864 B -> 4 blocks/CU by LDS

template <bool A_IS_BF16>
static __device__ __forceinline__ void gemm64_body(const void* __restrict__ Ap,
                                                   const unsigned short* __restrict__ Wt,
                                                   unsigned short* __restrict__ C,
                                                   const int M, const int K,
                                                   char* smem, int bid) {
    unsigned short* Bs0 = (unsigned short*)smem;               // 128 x LDPB
    unsigned short* Bs1 = (unsigned short*)smem + 128 * LDPB;  // 128 x LDPB
    const int tid = threadIdx.x;
    const int wave = tid >> 6;
    const int lane = tid & 63;
    const int ln = lane & 15;
    const int quad = lane >> 4;
    const int row0 = bid * 64;

    const int arow = row0 + wave * 16 + ln;  // this lane's exclusive A row
    const bool aOk = arow < M;
    const unsigned short* Abf = (const unsigned short*)Ap + (size_t)arow * K + quad * 8;
    const float* Af = (const float*)Ap + (size_t)arow * K + quad * 8;

    const int bn = tid >> 1;        // B staging col(n) 0..127
    const int bk = (tid & 1) * 32;  // B staging k-offset (32 elems = 4x bf16x8)
    const unsigned short* Bg = Wt + (size_t)bn * K + bk;

    const int NK = K >> 6;  // 8 (K=512) or 2 (K=128)

    f32x4 acc[8];
#pragma unroll
    for (int t = 0; t < 8; ++t) acc[t] = (f32x4){0.f, 0.f, 0.f, 0.f};

    // static-named prefetch registers (rule #20: no runtime-indexed vec arrays)
    bf16x8 qb0, qb1, qb2, qb3;       // B k-step in flight
    bf16x8 pva0, pva1;               // A bf16 path
    float4 pf0, pf1, pf2, pf3;       // A f32 path

#define GV2_LOAD_A(kc)                                                       \
    do {                                                                     \
        if (A_IS_BF16) {                                                     \
            if (aOk) {                                                       \
                pva0 = *(const bf16x8*)(Abf + (kc));                         \
                pva1 = *(const bf16x8*)(Abf + (kc) + 32);                    \
            }                                                                \
        } else {                                                             \
            if (aOk) {                                                       \
                pf0 = *(const float4*)(Af + (kc));                           \
                pf1 = *(const float4*)(Af + (kc) + 4);                       \
                pf2 = *(const float4*)(Af + (kc) + 32);                      \
                pf3 = *(const float4*)(Af + (kc) + 36);                      \
            }                                                                \
        }                                                                    \
    } while (0)

#define GV2_LOAD_B(kc)                                                       \
    do {                                                                     \
        qb0 = *(const bf16x8*)(Bg + (kc));                                   \
        qb1 = *(const bf16x8*)(Bg + (kc) + 8);                               \
        qb2 = *(const bf16x8*)(Bg + (kc) + 16);                              \
        qb3 = *(const bf16x8*)(Bg + (kc) + 24);                              \
    } while (0)

#define GV2_STORE_B(Bdst)                                                    \
    do {                                                                     \
        *(bf16x8*)&(Bdst)[bn * LDPB + bk] = qb0;                             \
        *(bf16x8*)&(Bdst)[bn * LDPB + bk + 8] = qb1;                         \
        *(bf16x8*)&(Bdst)[bn * LDPB + bk + 16] = qb2;                        \
        *(bf16x8*)&(Bdst)[bn * LDPB + bk + 24] = qb3;                        \
    } while (0)

    // prologue: stage B(0), keep B(1) in flight, A(0) in flight
    GV2_LOAD_B(0);
    GV2_STORE_B(Bs0);
    GV2_LOAD_A(0);
    if (NK > 1) GV2_LOAD_B(64);
    __syncthreads();

    for (int i = 0; i < NK; ++i) {
        unsigned short* Bcur = (i & 1) ? Bs1 : Bs0;
        unsigned short* Bnxt = (i & 1) ? Bs0 : Bs1;

        // materialize this step's A fragments from prefetch regs
        bf16x8 a0, a1;
        if (A_IS_BF16) {
            if (aOk) {
                a0 = pva0;
                a1 = pva1;
            } else {
#pragma unroll
                for (int j = 0; j < 8; ++j) { a0[j] = 0; a1[j] = 0; }
            }
        } else {
            if (aOk) {
                a0[0] = (short)f2bf(pf0.x); a0[1] = (short)f2bf(pf0.y);
                a0[2] = (short)f2bf(pf0.z); a0[3] = (short)f2bf(pf0.w);
                a0[4] = (short)f2bf(pf1.x); a0[5] = (short)f2bf(pf1.y);
                a0[6] = (short)f2bf(pf1.z); a0[7] = (short)f2bf(pf1.w);
                a1[0] = (short)f2bf(pf2.x); a1[1] = (short)f2bf(pf2.y);
                a1[2] = (short)f2bf(pf2.z); a1[3] = (short)f2bf(pf2.w);
                a1[4] = (short)f2bf(pf3.x); a1[5] = (short)f2bf(pf3.y);
                a1[6] = (short)f2bf(pf3.z); a1[7] = (short)f2bf(pf3.w);
            } else {
#pragma unroll
                for (int j = 0; j < 8; ++j) { a0[j] = 0; a1[j] = 0; }
            }
        }
        if (i + 1 < NK) GV2_LOAD_A((i + 1) * 64);  // depth-1 A prefetch

#pragma unroll
        for (int t = 0; t < 8; ++t) {
            bf16x8 b0 = *(const bf16x8*)&Bcur[(t * 16 + ln) * LDPB + quad * 8];
            acc[t] = __builtin_amdgcn_mfma_f32_16x16x32_bf16(a0, b0, acc[t], 0, 0, 0);
        }
#pragma unroll
        for (int t = 0; t < 8; ++t) {
            bf16x8 b1 = *(const bf16x8*)&Bcur[(t * 16 + ln) * LDPB + 32 + quad * 8];
            acc[t] = __builtin_amdgcn_mfma_f32_16x16x32_bf16(a1, b1, acc[t], 0, 0, 0);
        }

        if (i + 1 < NK) {
            GV2_STORE_B(Bnxt);  // safe: barrier at end of step i-1 drained readers
            if (i + 2 < NK) GV2_LOAD_B((i + 2) * 64);
        }
        __syncthreads();
    }

#undef GV2_LOAD_A
#undef GV2_LOAD_B
#undef GV2_STORE_B

#pragma unroll
    for (int t = 0; t < 8; ++t) {
#pragma unroll
        for (int r = 0; r < 4; ++r) {
            int row = row0 + wave * 16 + quad * 4 + r;
            if (row < M) C[(size_t)row * 128 + t * 16 + ln] = f2bf(acc[t][r]);
        }
    }
}

// ---------------- bin body v2: block-local counting sort -> coalesced writes --------
// Record: x = src | (dstLow8)<<16 ; y = fp32 weight bits.
// Old version scattered 1.6M 8B stores to random buckets (64 random cache lines
// per store instr = ~100MB partial-line RMW through L2 co-running with GEMM1).
// v2 sorts the block's 4096 records by bucket in LDS, then writes each bucket's
// run contiguously (avg 21 recs = 3 lines, lane-coalesced).
// LDS: recs 32768B + 4x256x4B = 36864B = GEMM_LDS_BYTES exactly.
static __device__ __forceinline__ void bin_body(const int* __restrict__ src,
                                                const int* __restrict__ dst,
                                                const float* __restrict__ w,
                                                int* __restrict__ bucketCursor,
                                                uint2* __restrict__ binned,
                                                int n, char* smem, int bid) {
    uint2* recs = (uint2*)smem;               // 4096 records
    int* hist = (int*)(smem + 32768);         // per-bucket count
    int* lincl = hist + 256;                  // inclusive scan of hist
    int* gbase = lincl + 256;                 // reserved global base per bucket
    int* cur = gbase + 256;                   // local placement cursor
    const int tid = threadIdx.x;
    const int wave = tid >> 6;
    const int lane = tid & 63;
    const int base = bid * 4096;

    hist[tid] = 0;
    __syncthreads();
#pragma unroll
    for (int r = 0; r < 16; ++r) {
        int e = base + r * 256 + tid;
        if (e < n) atomicAdd(&hist[dst[e] >> 8], 1);
    }
    __syncthreads();
    int v = hist[tid];
    lincl[tid] = v;
    __syncthreads();
    for (int off = 1; off < 256; off <<= 1) {
        int t = (tid >= off) ? lincl[tid - off] : 0;
        __syncthreads();
        lincl[tid] += t;
        __syncthreads();
    }
    if (tid < NBUCKETS && v > 0) gbase[tid] = atomicAdd(&bucketCursor[tid], v);
    cur[tid] = lincl[tid] - v;  // exclusive prefix = local start
    __syncthreads();
#pragma unroll
    for (int r = 0; r < 16; ++r) {
        int e = base + r * 256 + tid;
        if (e < n) {
            int d = dst[e];
            int pos = atomicAdd(&cur[d >> 8], 1);
            uint2 rec;
            rec.x = (unsigned int)src[e] | ((unsigned int)(d & 255) << 16);
            rec.y = asu32_f(w[e]);
            recs[pos] = rec;
        }
    }
    __syncthreads();
    // wave j flushes buckets j, j+4, ... : contiguous run per bucket
    for (int B = wave; B < NBUCKETS; B += 4) {
        int cnt = hist[B];
        if (cnt == 0) continue;
        int lst = lincl[B] - cnt;
        int g = gbase[B];
        for (int i = lane; i < cnt; i += 64) binned[g + i] = recs[lst + i];
    }
}

// ---------------- fused: GEMM1 (782 blocks) || bin (391 blocks) ----------------
#define GEMM1_BLOCKS 782
#define BIN_BLOCKS 391
__global__ __launch_bounds__(256) void fused_gemm1_bin(const float* __restrict__ x,
                                                       const unsigned short* __restrict__ Wt1,
                                                       unsigned short* __restrict__ tb,
                                                       const int* __restrict__ src,
                                                       const int* __restrict__ dst,
                                                       const float* __restrict__ w,
                                                       int* __restrict__ bucketCursor,
                                                       uint2* __restrict__ binned) {
    __shared__ char smem[GEMM_LDS_BYTES];
    if (blockIdx.x < GEMM1_BLOCKS) {
        gemm64_body<false>(x, Wt1, tb, N_NODES, NFEAT, smem, blockIdx.x);
    } else {
        bin_body(src, dst, w, bucketCursor, binned, N_EDGES, smem,
                 blockIdx.x - GEMM1_BLOCKS);
    }
}

// ---------------- standalone GEMM layer 2 ----------------
__global__ __launch_bounds__(256) void gemm64_l2(const unsigned short* __restrict__ A,
                                                 const unsigned short* __restrict__ Wt,
                                                 unsigned short* __restrict__ C) {
    __shared__ char smem[GEMM_LDS_BYTES];
    gemm64_body<true>(A, Wt, C, N_NODES, NHID, smem, blockIdx.x);
}

// ---------------- build_csr (inline bucket scan): 4B edge records ----------------
// pairs[pos] = src(16b) | bf16(weight)(16b high)
// 1024 threads/block: 196 blocks = 0.77 blocks/CU, so per-block latency IS the
// kernel duration -- 4x threads = 4x fewer serial iterations per block.
__global__ __launch_bounds__(1024) void build_csr(const uint2* __restrict__ binned,
                                                  const int* __restrict__ bucketCursor,
                                                  unsigned int* __restrict__ pairs,
                                                  int* __restrict__ row_ptr) {
    __shared__ int bs[256];
    __shared__ int hist[256];
    __shared__ int sc[256];
    __shared__ int cur[256];
    const int b = blockIdx.x;
    const int tid = threadIdx.x;

    // inline exclusive scan of bucket fills (tid<256 participate; all sync)
    if (tid < 256) bs[tid] = (tid < NBUCKETS) ? (bucketCursor[tid] - tid * BUCKET_CAP) : 0;
    if (tid < 256) hist[tid] = 0;
    __syncthreads();
    for (int off = 1; off < 256; off <<= 1) {
        int t = 0;
        if (tid < 256 && tid >= off) t = bs[tid - off];
        __syncthreads();
        if (tid < 256) bs[tid] += t;
        __syncthreads();
    }
    const int cnt = bucketCursor[b] - b * BUCKET_CAP;
    const int segStart = bs[b] - cnt;  // exclusive prefix at b
    if (b == NBUCKETS - 1 && tid == 0) row_ptr[N_NODES] = bs[NBUCKETS - 1];
    const uint2* seg = binned + (size_t)b * BUCKET_CAP;

    for (int i = tid; i < cnt; i += 1024)
        atomicAdd(&hist[seg[i].x >> 16], 1);
    __syncthreads();
    if (tid < 256) {
        int v = hist[tid];
        sc[tid] = v;
    }
    __syncthreads();
    for (int off = 1; off < 256; off <<= 1) {
        int t = 0;
        if (tid < 256 && tid >= off) t = sc[tid - off];
        __syncthreads();
        if (tid < 256) sc[tid] += t;
        __syncthreads();
    }
    if (tid < 256) {
        int excl = sc[tid] - hist[tid];
        int node = b * 256 + tid;
        if (node < N_NODES) row_ptr[node] = segStart + excl;
        cur[tid] = segStart + excl;
    }
    __syncthreads();
    for (int i = tid; i < cnt; i += 1024) {
        uint2 p = seg[i];
        int pos = atomicAdd(&cur[p.x >> 16], 1);
        pairs[pos] = (p.x & 0xFFFFu) | ((unsigned int)f2bf(asfloat_u32(p.y)) << 16);
    }
}

// ---------------- GEMM, N=64(->40 valid), K=128, MFMA, fully-staged ----------------
// C64[M x 64](bf16) = A[M x 128](bf16) @ Wt2^T ; Wt2 is [64][128] bf16, cols 40+ zero.
// Output rows PADDED to 64 cols (128B, aligned) so the softmax gather can use
// 16-lane x uint2 groups. Cols 40..63 are exact zeros (Wt2 zero-padded).
#define LDP2 136
__global__ __launch_bounds__(256) void gemm_n64(const unsigned short* __restrict__ A,
                                                const unsigned short* __restrict__ Wt2,
                                                unsigned short* __restrict__ C, int M) {
    __shared__ unsigned short As[64 * LDP2];
    __shared__ unsigned short Bs[64 * LDP2];
    const int tid = threadIdx.x;
    const int wave = tid >> 6;
    const int lane = tid & 63;
    const int ln = lane & 15;
    const int quad = lane >> 4;
    const int row0 = blockIdx.x * 64;

#pragma unroll
    for (int i = 0; i < 4; ++i) {  // A: 64 rows x 128 = 1024 chunks of 8
        int q = tid + 256 * i;
        int r = q >> 4;
        int c = (q & 15) * 8;
        bf16x8 v;
        if (row0 + r < M) {
            v = *(const bf16x8*)(A + (size_t)(row0 + r) * 128 + c);
        } else {
#pragma unroll
            for (int j = 0; j < 8; ++j) v[j] = 0;
        }
        *(bf16x8*)&As[r * LDP2 + c] = v;
    }
#pragma unroll
    for (int i = 0; i < 4; ++i) {  // B: 64 rows x 128 = 1024 chunks of 8
        int q = tid + 256 * i;
        int r = q >> 4;
        int c = (q & 15) * 8;
        *(bf16x8*)&Bs[r * LDP2 + c] = *(const bf16x8*)(Wt2 + (size_t)r * 128 + c);
    }
    __syncthreads();

    f32x4 acc[4];
#pragma unroll
    for (int t = 0; t < 4; ++t) acc[t] = (f32x4){0.f, 0.f, 0.f, 0.f};

#pragma unroll
    for (int kc = 0; kc < 128; kc += 32) {
        bf16x8 a = *(const bf16x8*)&As[(wave * 16 + ln) * LDP2 + kc + quad * 8];
#pragma unroll
        for (int t = 0; t < 4; ++t) {
            bf16x8 b = *(const bf16x8*)&Bs[(t * 16 + ln) * LDP2 + kc + quad * 8];
            acc[t] = __builtin_amdgcn_mfma_f32_16x16x32_bf16(a, b, acc[t], 0, 0, 0);
        }
    }

#pragma unroll
    for (int t = 0; t < 4; ++t) {
#pragma unroll
        for (int r = 0; r < 4; ++r) {
            int row = row0 + wave * 16 + quad * 4 + r;
            if (row < M) C[(size_t)row * 64 + t * 16 + ln] = f2bf(acc[t][r]);
        }
    }
}

// ---------------- SpMM (CSR gather, bf16 rows) + bias + ReLU, feat=128 ----------------
// One wave per dst node, FOUR 16-lane groups, full 256B row per group, 32 edges
// in flight per wave. (r1/r2/r3: MLP increases were all ~neutral -> this kernel
// is at its memory-service bound; structure frozen.)
__global__ __launch_bounds__(256) void spmm_bias_relu_bf16(const unsigned short* __restrict__ t,
                                                           const int* __restrict__ row_ptr,
                                                           const unsigned int* __restrict__ pairs,
                                                           const float* __restrict__ bias,
                                                           unsigned short* __restrict__ out) {
    const int node = blockIdx.x * 4 + (threadIdx.x >> 6);
    const int lane = threadIdx.x & 63;
    const int g = lane >> 4;        // group 0..3
    const int fl = (lane & 15) * 8; // feature base: 8 bf16 = 16B owned by this lane
    const int e0 = row_ptr[node];
    const int e1 = row_ptr[node + 1];
    float acc8[8];
#pragma unroll
    for (int j = 0; j < 8; ++j) acc8[j] = 0.f;

    int e = e0;
    for (; e + 32 <= e1; e += 32) {
        unsigned int p[8];
        uint4 v[8];
#pragma unroll
        for (int i = 0; i < 8; ++i) p[i] = pairs[e + 4 * i + g];
#pragma unroll
        for (int i = 0; i < 8; ++i)
            v[i] = *(const uint4*)(t + (size_t)(p[i] & 0xFFFFu) * 128 + fl);
#pragma unroll
        for (int i = 0; i < 8; ++i) {
            float w = asfloat_u32(p[i] & 0xFFFF0000u);
            acc8[0] += w * asfloat_u32(v[i].x << 16);
            acc8[1] += w * asfloat_u32(v[i].x & 0xFFFF0000u);
            acc8[2] += w * asfloat_u32(v[i].y << 16);
            acc8[3] += w * asfloat_u32(v[i].y & 0xFFFF0000u);
            acc8[4] += w * asfloat_u32(v[i].z << 16);
            acc8[5] += w * asfloat_u32(v[i].z & 0xFFFF0000u);
            acc8[6] += w * asfloat_u32(v[i].w << 16);
            acc8[7] += w * asfloat_u32(v[i].w & 0xFFFF0000u);
        }
    }
    for (; e + 4 <= e1; e += 4) {
        unsigned int p = pairs[e + g];
        uint4 v = *(const uint4*)(t + (size_t)(p & 0xFFFFu) * 128 + fl);
        float w = asfloat_u32(p & 0xFFFF0000u);
        acc8[0] += w * asfloat_u32(v.x << 16);
        acc8[1] += w * asfloat_u32(v.x & 0xFFFF0000u);
        acc8[2] += w * asfloat_u32(v.y << 16);
        acc8[3] += w * asfloat_u32(v.y & 0xFFFF0000u);
        acc8[4] += w * asfloat_u32(v.z << 16);
        acc8[5] += w * asfloat_u32(v.z & 0xFFFF0000u);
        acc8[6] += w * asfloat_u32(v.w << 16);
        acc8[7] += w * asfloat_u32(v.w & 0xFFFF0000u);
    }
    if (g < e1 - e) {  // remainder 0..3 edges, one per group
        unsigned int p = pairs[e + g];
        uint4 v = *(const uint4*)(t + (size_t)(p & 0xFFFFu) * 128 + fl);
        float w = asfloat_u32(p & 0xFFFF0000u);
        acc8[0] += w * asfloat_u32(v.x << 16);
        acc8[1] += w * asfloat_u32(v.x & 0xFFFF0000u);
        acc8[2] += w * asfloat_u32(v.y << 16);
        acc8[3] += w * asfloat_u32(v.y & 0xFFFF0000u);
        acc8[4] += w * asfloat_u32(v.z << 16);
        acc8[5] += w * asfloat_u32(v.z & 0xFFFF0000u);
        acc8[6] += w * asfloat_u32(v.w << 16);
        acc8[7] += w * asfloat_u32(v.w & 0xFFFF0000u);
    }
    // lanes l, l^16, l^32, l^48 own the same 8 features -> butterfly over groups
#pragma unroll
    for (int j = 0; j < 8; ++j) {
        acc8[j] += __shfl_xor(acc8[j], 16);
        acc8[j] += __shfl_xor(acc8[j], 32);
    }
    if (g == 0) {
        float4 b0 = *(const float4*)&bias[fl];
        float4 b1 = *(const float4*)&bias[fl + 4];
        acc8[0] = fmaxf(acc8[0] + b0.x, 0.f);
        acc8[1] = fmaxf(acc8[1] + b0.y, 0.f);
        acc8[2] = fmaxf(acc8[2] + b0.z, 0.f);
        acc8[3] = fmaxf(acc8[3] + b0.w, 0.f);
        acc8[4] = fmaxf(acc8[4] + b1.x, 0.f);
        acc8[5] = fmaxf(acc8[5] + b1.y, 0.f);
        acc8[6] = fmaxf(acc8[6] + b1.z, 0.f);
        acc8[7] = fmaxf(acc8[7] + b1.w, 0.f);
        uint4 o;
        o.x = ((unsigned int)f2bf(acc8[0])) | (((unsigned int)f2bf(acc8[1])) << 16);
        o.y = ((unsigned int)f2bf(acc8[2])) | (((unsigned int)f2bf(acc8[3])) << 16);
        o.z = ((unsigned int)f2bf(acc8[4])) | (((unsigned int)f2bf(acc8[5])) << 16);
        o.w = ((unsigned int)f2bf(acc8[6])) | (((unsigned int)f2bf(acc8[7])) << 16);
        *(uint4*)(out + (size_t)node * 128 + fl) = o;
    }
}

// ---------------- SpMM feat=64pad (bf16 rows) + bias + log_softmax ----------------
// t rows are 64 bf16 = 128B aligned (cols 40+ zero). FOUR 16-lane groups, each
// gathers a full row via uint2 (8B = 4 feats) -> 4 edges/instr, 32 in flight.
// Butterfly (xor 16,32) leaves every lane with the full per-class sums; softmax
// reduces over the 16-lane feature split (xor 1,2,4,8). Lane l&15 owns classes
// 4l..4l+3; lanes with (lane&15)>=10 hold only pad classes.
__global__ __launch_bounds__(256) void spmm_logsoftmax(const unsigned short* __restrict__ t,
                                                       const int* __restrict__ row_ptr,
                                                       const unsigned int* __restrict__ pairs,
                                                       const float* __restrict__ bias,
                                                       float* __restrict__ out) {
    const int node = blockIdx.x * 4 + (threadIdx.x >> 6);
    const int lane = threadIdx.x & 63;
    const int g = lane >> 4;
    const int fe = (lane & 15) * 4;  // element base (4 bf16 = 8B)
    const int e0 = row_ptr[node];
    const int e1 = row_ptr[node + 1];
    float a0 = 0.f, a1 = 0.f, a2 = 0.f, a3 = 0.f;
    int e = e0;
    for (; e + 32 <= e1; e += 32) {
        unsigned int p[8];
        uint2 v[8];
#pragma unroll
        for (int i = 0; i < 8; ++i) p[i] = pairs[e + 4 * i + g];
#pragma unroll
        for (int i = 0; i < 8; ++i)
            v[i] = *(const uint2*)(t + (size_t)(p[i] & 0xFFFFu) * 64 + fe);
#pragma unroll
        for (int i = 0; i < 8; ++i) {
            float w = asfloat_u32(p[i] & 0xFFFF0000u);
            a0 += w * asfloat_u32(v[i].x << 16);
            a1 += w * asfloat_u32(v[i].x & 0xFFFF0000u);
            a2 += w * asfloat_u32(v[i].y << 16);
            a3 += w * asfloat_u32(v[i].y & 0xFFFF0000u);
        }
    }
    for (; e + 4 <= e1; e += 4) {
        unsigned int p = pairs[e + g];
        uint2 v = *(const uint2*)(t + (size_t)(p & 0xFFFFu) * 64 + fe);
        float w = asfloat_u32(p & 0xFFFF0000u);
        a0 += w * asfloat_u32(v.x << 16);
        a1 += w * asfloat_u32(v.x & 0xFFFF0000u);
        a2 += w * asfloat_u32(v.y << 16);
        a3 += w * asfloat_u32(v.y & 0xFFFF0000u);
    }
    if (g < e1 - e) {
        unsigned int p = pairs[e + g];
        uint2 v = *(const uint2*)(t + (size_t)(p & 0xFFFFu) * 64 + fe);
        float w = asfloat_u32(p & 0xFFFF0000u);
        a0 += w * asfloat_u32(v.x << 16);
        a1 += w * asfloat_u32(v.x & 0xFFFF0000u);
        a2 += w * asfloat_u32(v.y << 16);
        a3 += w * asfloat_u32(v.y & 0xFFFF0000u);
    }
    a0 += __shfl_xor(a0, 16); a0 += __shfl_xor(a0, 32);
    a1 += __shfl_xor(a1, 16); a1 += __shfl_xor(a1, 32);
    a2 += __shfl_xor(a2, 16); a2 += __shfl_xor(a2, 32);
    a3 += __shfl_xor(a3, 16); a3 += __shfl_xor(a3, 32);

    const bool valid = (lane & 15) < 10;  // classes fe..fe+3 < 40
    float l0 = -INFINITY, l1 = -INFINITY, l2 = -INFINITY, l3 = -INFINITY;
    if (valid) {
        float4 b = *(const float4*)&bias[fe];
        l0 = a0 + b.x; l1 = a1 + b.y; l2 = a2 + b.z; l3 = a3 + b.w;
    }
    float m = fmaxf(fmaxf(l0, l1), fmaxf(l2, l3));
#pragma unroll
    for (int off = 8; off; off >>= 1) m = fmaxf(m, __shfl_xor(m, off));
    float s = valid ? (__expf(l0 - m) + __expf(l1 - m) + __expf(l2 - m) + __expf(l3 - m)) : 0.f;
#pragma unroll
    for (int off = 8; off; off >>= 1) s += __shfl_xor(s, off);
    if (valid && g == 0) {
        float ls = __logf(s);
        float4 o;
        o.x = l0 - m - ls; o.y = l1 - m - ls; o.z = l2 - m - ls; o.w = l3 - m - ls;
        *(float4*)&out[(size_t)node * NCLASS + fe] = o;
    }
}

// ---------------- launch ----------------

extern "C" void kernel_launch(void* const* d_in, const int* in_sizes, int n_in,
                              void* d_out, int out_size, void* d_ws, size_t ws_size,
                              hipStream_t stream) {
    const float* x = (const float*)d_in[0];
    const int* edge_src = (const int*)d_in[1];
    const int* edge_dst = (const int*)d_in[2];
    const float* edge_weight = (const float*)d_in[3];
    const float* W1 = (const float*)d_in[4];
    const float* b1 = (const float*)d_in[5];
    const float* Wh = (const float*)d_in[6];
    const float* bh = (const float*)d_in[7];
    const float* W2 = (const float*)d_in[8];
    const float* b2 = (const float*)d_in[9];
    float* out = (float*)d_out;

    size_t off = 0;
    auto carve = [&](size_t bytes) {
        void* p = (char*)d_ws + off;
        off += (bytes + 511) & ~(size_t)511;
        return p;
    };
    unsigned short* tb = (unsigned short*)carve((size_t)N_NODES * 128 * 2);
    unsigned short* hb = (unsigned short*)carve((size_t)N_NODES * 128 * 2);
    unsigned short* t3 = (unsigned short*)carve((size_t)N_NODES * 64 * 2);
    unsigned short* Wt1 = (unsigned short*)carve((size_t)NFEAT * NHID * 2);
    unsigned short* Wth = (unsigned short*)carve((size_t)NHID * NHID * 2);
    unsigned short* Wt2 = (unsigned short*)carve((size_t)64 * NHID * 2);
    int* row_ptr = (int*)carve((size_t)(N_NODES + 4) * 4);
    int* bucketCursor = (int*)carve((size_t)NBUCKETS * 4);
    uint2* binned = (uint2*)carve((size_t)NBUCKETS * BUCKET_CAP * 8);
    unsigned int* pairs = (unsigned int*)carve((size_t)N_EDGES * 4);
    (void)ws_size; (void)n_in; (void)in_sizes; (void)out_size;

    const int prepBlocks =
        (NFEAT * NHID + NHID * NHID + 64 * NHID + NBUCKETS + 255) / 256;  // 353
    const int spmmBlocks = N_NODES / 4;            // 12500
    const int gemmBlocks = (N_NODES + 63) / 64;    // 782

    // prep (weights + cursors)
    prep_kernel<<<prepBlocks, 256, 0, stream>>>(W1, Wt1, Wh, Wth, W2, Wt2, bucketCursor);

    // GEMM1 || bin (independent work fused into one launch)
    fused_gemm1_bin<<<GEMM1_BLOCKS + BIN_BLOCKS, 256, 0, stream>>>(
        x, Wt1, tb, edge_src, edge_dst, edge_weight, bucketCursor, binned);

    // CSR finalize (inline bucket scan; 1024 thr -- 196 blocks are latency-critical)
    build_csr<<<NBUCKETS, 1024, 0, stream>>>(binned, bucketCursor, pairs, row_ptr);

    // Layer 1 aggregate
    spmm_bias_relu_bf16<<<spmmBlocks, 256, 0, stream>>>(tb, row_ptr, pairs, b1, hb);

    // Layer 2
    gemm64_l2<<<gemmBlocks, 256, 0, stream>>>(hb, Wth, tb);
    spmm_bias_relu_bf16<<<spmmBlocks, 256, 0, stream>>>(tb, row_ptr, pairs, bh, hb);

    // Layer 3 (MFMA, fully-staged tiles, 64-col padded output)
    gemm_n64<<<gemmBlocks, 256, 0, stream>>>(hb, Wt2, t3, N_NODES);
    spmm_logsoftmax<<<spmmBlocks, 256, 0, stream>>>(t3, row_ptr, pairs, b2, out);
}

// Round 5
// 360.382 us; speedup vs baseline: 1.2128x; 1.0721x over previous
//
#include <hip/hip_runtime.h>
#include <hip/hip_bf16.h>
#include <hip/hip_fp8.h>
#include <math.h>

#define N_NODES 50000
#define N_EDGES 1600000
#define NFEAT 512
#define NHID 128
#define NCLASS 40

#define NBUCKETS 196      // ceil(N_NODES / 256), dst>>8
#define BUCKET_CAP 16384  // avg fill ~8163 -> huge margin

typedef __attribute__((ext_vector_type(8))) short bf16x8;
typedef __attribute__((ext_vector_type(4))) float f32x4;
typedef __attribute__((ext_vector_type(2))) float f32x2;

static __device__ __forceinline__ float asfloat_u32(unsigned int u) {
    union { unsigned int u; float f; } c;
    c.u = u;
    return c.f;
}
static __device__ __forceinline__ unsigned int asu32_f(float f) {
    union { float f; unsigned int u; } c;
    c.f = f;
    return c.u;
}
static __device__ __forceinline__ unsigned short f2bf(float f) {
    union { float f; unsigned int u; } c;
    c.f = f;
    unsigned int r = c.u + 0x7FFFu + ((c.u >> 16) & 1u);  // RTN-even
    return (unsigned short)(r >> 16);
}

// ---------- fp8 e4m3fn (OCP) helpers ----------
// exact bit-trick dequant: val = asfloat((e|m)<<20) * 2^120, works for normals
// AND subnormals (f32-subnormal path scales exactly); inputs are never NaN.
static __device__ __forceinline__ float fp8_to_f32_sw(unsigned int x) {
    float m = asfloat_u32((x & 0x7Fu) << 20) * 0x1p+120f;
    return asfloat_u32(asu32_f(m) | ((x & 0x80u) << 24));
}
static __device__ __forceinline__ void dq4(unsigned int u, float* f) {
#if __has_builtin(__builtin_amdgcn_cvt_pk_f32_fp8)
    f32x2 lo = __builtin_amdgcn_cvt_pk_f32_fp8(u, false);
    f32x2 hi = __builtin_amdgcn_cvt_pk_f32_fp8(u, true);
    f[0] = lo[0]; f[1] = lo[1]; f[2] = hi[0]; f[3] = hi[1];
#else
    f[0] = fp8_to_f32_sw(u & 0xFFu);
    f[1] = fp8_to_f32_sw((u >> 8) & 0xFFu);
    f[2] = fp8_to_f32_sw((u >> 16) & 0xFFu);
    f[3] = fp8_to_f32_sw((u >> 24) & 0xFFu);
#endif
}
static __device__ __forceinline__ unsigned char f2fp8(float f) {
#if __has_builtin(__builtin_amdgcn_cvt_pk_fp8_f32)
    int v = __builtin_amdgcn_cvt_pk_fp8_f32(f, f, 0, false);
    return (unsigned char)(v & 0xFF);
#else
    __hip_fp8_e4m3 h(f);
    return (unsigned char)h.__x;
#endif
}

// ---------------- prep: bucket cursors + weight transposes (W1, Wh, W2) ----------------
// Wt2 is [64][128] bf16: Wt2[n][k] = W2[k][n] for n<40, 0 for 40<=n<64 (MFMA col padding).
__global__ __launch_bounds__(256) void prep_kernel(const float* __restrict__ W1,
                                                   unsigned short* __restrict__ Wt1,
                                                   const float* __restrict__ Wh,
                                                   unsigned short* __restrict__ Wth,
                                                   const float* __restrict__ W2,
                                                   unsigned short* __restrict__ Wt2,
                                                   int* __restrict__ bucketCursor) {
    int idx = blockIdx.x * 256 + threadIdx.x;
    if (idx < NFEAT * NHID) {  // Wt1[n][k] = bf16(W1[k][n])
        int k = idx >> 7;
        int n = idx & 127;
        Wt1[(size_t)n * NFEAT + k] = f2bf(W1[idx]);
    } else if (idx < NFEAT * NHID + NHID * NHID) {
        int j = idx - NFEAT * NHID;
        int k = j >> 7;
        int n = j & 127;
        Wth[(size_t)n * NHID + k] = f2bf(Wh[j]);
    } else if (idx < NFEAT * NHID + NHID * NHID + 64 * NHID) {
        int j = idx - (NFEAT * NHID + NHID * NHID);
        int n = j & 63;
        int k = j >> 6;
        Wt2[(size_t)n * NHID + k] = (n < NCLASS) ? f2bf(W2[(size_t)k * NCLASS + n]) : 0;
    } else {
        int j = idx - (NFEAT * NHID + NHID * NHID + 64 * NHID);
        if (j < NBUCKETS) bucketCursor[j] = j * BUCKET_CAP;
    }
}

// ---------------- GEMM (64-row tile) body, N=128, BK=64, A-direct, 18KB LDS --------
// C[M x 128] = A[M x K] @ Wt^T ; Wt is [128][K] bf16. Output bf16 or fp8 (tables).
// r2-r4 lessons baked in: (a) A-fragment is per-lane-exclusive -> global->reg
// direct, A never touches LDS; (b) BK=64 (r3: beats BK=32); (c) LDS must stay
// small: grid needs 4.58 blocks/CU, r4's 36.9KB capped residency at 4 -> regress.
// Single-buffered B (128 x LDPB = 18.4KB), loads issued before the barriers.
#define LDPB 72
#define GEMM_LDS_BYTES (128 * LDPB * 2)  // 18432 B

template <bool A_IS_BF16, bool OUT_FP8>
static __device__ __forceinline__ void gemm64_body(const void* __restrict__ Ap,
                                                   const unsigned short* __restrict__ Wt,
                                                   void* __restrict__ Cv,
                                                   const int M, const int K,
                                                   char* smem, int bid) {
    unsigned short* Bs = (unsigned short*)smem;  // 128 x LDPB
    const int tid = threadIdx.x;
    const int wave = tid >> 6;
    const int lane = tid & 63;
    const int ln = lane & 15;
    const int quad = lane >> 4;
    const int row0 = bid * 64;

    const int arow = row0 + wave * 16 + ln;  // this lane's exclusive A row
    const bool aOk = arow < M;
    const unsigned short* Abf = (const unsigned short*)Ap + (size_t)arow * K + quad * 8;
    const float* Af = (const float*)Ap + (size_t)arow * K + quad * 8;

    const int bn = tid >> 1;        // B staging col(n) 0..127
    const int bk = (tid & 1) * 32;  // B staging k-offset (32 elems = 4x bf16x8)
    const unsigned short* Bg = Wt + (size_t)bn * K + bk;

    f32x4 acc[8];
#pragma unroll
    for (int t = 0; t < 8; ++t) acc[t] = (f32x4){0.f, 0.f, 0.f, 0.f};

    for (int kc = 0; kc < K; kc += 64) {
        // issue global loads (B tile + this lane's A slice) before the barriers
        bf16x8 qb0 = *(const bf16x8*)(Bg + kc);
        bf16x8 qb1 = *(const bf16x8*)(Bg + kc + 8);
        bf16x8 qb2 = *(const bf16x8*)(Bg + kc + 16);
        bf16x8 qb3 = *(const bf16x8*)(Bg + kc + 24);

        bf16x8 a0, a1;
        if (A_IS_BF16) {
            if (aOk) {
                a0 = *(const bf16x8*)(Abf + kc);
                a1 = *(const bf16x8*)(Abf + kc + 32);
            } else {
#pragma unroll
                for (int j = 0; j < 8; ++j) { a0[j] = 0; a1[j] = 0; }
            }
        } else {
            if (aOk) {
                float4 f0 = *(const float4*)(Af + kc);
                float4 f1 = *(const float4*)(Af + kc + 4);
                float4 f2 = *(const float4*)(Af + kc + 32);
                float4 f3 = *(const float4*)(Af + kc + 36);
                a0[0] = (short)f2bf(f0.x); a0[1] = (short)f2bf(f0.y);
                a0[2] = (short)f2bf(f0.z); a0[3] = (short)f2bf(f0.w);
                a0[4] = (short)f2bf(f1.x); a0[5] = (short)f2bf(f1.y);
                a0[6] = (short)f2bf(f1.z); a0[7] = (short)f2bf(f1.w);
                a1[0] = (short)f2bf(f2.x); a1[1] = (short)f2bf(f2.y);
                a1[2] = (short)f2bf(f2.z); a1[3] = (short)f2bf(f2.w);
                a1[4] = (short)f2bf(f3.x); a1[5] = (short)f2bf(f3.y);
                a1[6] = (short)f2bf(f3.z); a1[7] = (short)f2bf(f3.w);
            } else {
#pragma unroll
                for (int j = 0; j < 8; ++j) { a0[j] = 0; a1[j] = 0; }
            }
        }

        __syncthreads();  // previous iteration's B readers done
        *(bf16x8*)&Bs[bn * LDPB + bk] = qb0;
        *(bf16x8*)&Bs[bn * LDPB + bk + 8] = qb1;
        *(bf16x8*)&Bs[bn * LDPB + bk + 16] = qb2;
        *(bf16x8*)&Bs[bn * LDPB + bk + 24] = qb3;
        __syncthreads();

#pragma unroll
        for (int t = 0; t < 8; ++t) {
            bf16x8 b0 = *(const bf16x8*)&Bs[(t * 16 + ln) * LDPB + quad * 8];
            acc[t] = __builtin_amdgcn_mfma_f32_16x16x32_bf16(a0, b0, acc[t], 0, 0, 0);
        }
#pragma unroll
        for (int t = 0; t < 8; ++t) {
            bf16x8 b1 = *(const bf16x8*)&Bs[(t * 16 + ln) * LDPB + 32 + quad * 8];
            acc[t] = __builtin_amdgcn_mfma_f32_16x16x32_bf16(a1, b1, acc[t], 0, 0, 0);
        }
    }

    if (OUT_FP8) {
        unsigned char* C8 = (unsigned char*)Cv;
#pragma unroll
        for (int t = 0; t < 8; ++t) {
#pragma unroll
            for (int r = 0; r < 4; ++r) {
                int row = row0 + wave * 16 + quad * 4 + r;
                if (row < M) C8[(size_t)row * 128 + t * 16 + ln] = f2fp8(acc[t][r]);
            }
        }
    } else {
        unsigned short* C = (unsigned short*)Cv;
#pragma unroll
        for (int t = 0; t < 8; ++t) {
#pragma unroll
            for (int r = 0; r < 4; ++r) {
                int row = row0 + wave * 16 + quad * 4 + r;
                if (row < M) C[(size_t)row * 128 + t * 16 + ln] = f2bf(acc[t][r]);
            }
        }
    }
}

// ---------------- bin body: bucket edges by dst>>8 (scatter; ~2KB LDS) ----------------
// Record: x = src | (dstLow8)<<16 ; y = fp32 weight bits.
// (r4's LDS counting-sort needed 36.9KB -> capped GEMM residency; net regression.
//  Scatter version keeps the fused kernel at 18.4KB.)
static __device__ __forceinline__ void bin_body(const int* __restrict__ src,
                                                const int* __restrict__ dst,
                                                const float* __restrict__ w,
                                                int* __restrict__ bucketCursor,
                                                uint2* __restrict__ binned,
                                                int n, char* smem, int bid) {
    int* hist = (int*)smem;            // NBUCKETS
    int* cur = (int*)smem + NBUCKETS;  // NBUCKETS
    const int tid = threadIdx.x;
    const int base = bid * 4096;
    if (tid < NBUCKETS) hist[tid] = 0;
    __syncthreads();
#pragma unroll
    for (int r = 0; r < 16; ++r) {
        int e = base + r * 256 + tid;
        if (e < n) atomicAdd(&hist[dst[e] >> 8], 1);
    }
    __syncthreads();
    if (tid < NBUCKETS && hist[tid] > 0)
        cur[tid] = atomicAdd(&bucketCursor[tid], hist[tid]);
    __syncthreads();
#pragma unroll
    for (int r = 0; r < 16; ++r) {
        int e = base + r * 256 + tid;
        if (e < n) {
            int d = dst[e];
            int pos = atomicAdd(&cur[d >> 8], 1);
            uint2 rec;
            rec.x = (unsigned int)src[e] | ((unsigned int)(d & 255) << 16);
            rec.y = asu32_f(w[e]);
            binned[pos] = rec;
        }
    }
}

// ---------------- fused: GEMM1 (782 blocks) || bin (391 blocks) ----------------
#define GEMM1_BLOCKS 782
#define BIN_BLOCKS 391
__global__ __launch_bounds__(256) void fused_gemm1_bin(const float* __restrict__ x,
                                                       const unsigned short* __restrict__ Wt1,
                                                       unsigned char* __restrict__ tb,
                                                       const int* __restrict__ src,
                                                       const int* __restrict__ dst,
                                                       const float* __restrict__ w,
                                                       int* __restrict__ bucketCursor,
                                                       uint2* __restrict__ binned) {
    __shared__ char smem[GEMM_LDS_BYTES];
    if (blockIdx.x < GEMM1_BLOCKS) {
        gemm64_body<false, true>(x, Wt1, tb, N_NODES, NFEAT, smem, blockIdx.x);
    } else {
        bin_body(src, dst, w, bucketCursor, binned, N_EDGES, smem,
                 blockIdx.x - GEMM1_BLOCKS);
    }
}

// ---------------- standalone GEMM layer 2 (bf16 A, fp8 table out) ----------------
__global__ __launch_bounds__(256) void gemm64_l2(const unsigned short* __restrict__ A,
                                                 const unsigned short* __restrict__ Wt,
                                                 unsigned char* __restrict__ C) {
    __shared__ char smem[GEMM_LDS_BYTES];
    gemm64_body<true, true>(A, Wt, C, N_NODES, NHID, smem, blockIdx.x);
}

// ---------------- build_csr (inline bucket scan): 4B edge records ----------------
// pairs[pos] = src(16b) | bf16(weight)(16b high)
__global__ __launch_bounds__(1024) void build_csr(const uint2* __restrict__ binned,
                                                  const int* __restrict__ bucketCursor,
                                                  unsigned int* __restrict__ pairs,
                                                  int* __restrict__ row_ptr) {
    __shared__ int bs[256];
    __shared__ int hist[256];
    __shared__ int sc[256];
    __shared__ int cur[256];
    const int b = blockIdx.x;
    const int tid = threadIdx.x;

    if (tid < 256) bs[tid] = (tid < NBUCKETS) ? (bucketCursor[tid] - tid * BUCKET_CAP) : 0;
    if (tid < 256) hist[tid] = 0;
    __syncthreads();
    for (int off = 1; off < 256; off <<= 1) {
        int t = 0;
        if (tid < 256 && tid >= off) t = bs[tid - off];
        __syncthreads();
        if (tid < 256) bs[tid] += t;
        __syncthreads();
    }
    const int cnt = bucketCursor[b] - b * BUCKET_CAP;
    const int segStart = bs[b] - cnt;  // exclusive prefix at b
    if (b == NBUCKETS - 1 && tid == 0) row_ptr[N_NODES] = bs[NBUCKETS - 1];
    const uint2* seg = binned + (size_t)b * BUCKET_CAP;

    for (int i = tid; i < cnt; i += 1024)
        atomicAdd(&hist[seg[i].x >> 16], 1);
    __syncthreads();
    if (tid < 256) {
        int v = hist[tid];
        sc[tid] = v;
    }
    __syncthreads();
    for (int off = 1; off < 256; off <<= 1) {
        int t = 0;
        if (tid < 256 && tid >= off) t = sc[tid - off];
        __syncthreads();
        if (tid < 256) sc[tid] += t;
        __syncthreads();
    }
    if (tid < 256) {
        int excl = sc[tid] - hist[tid];
        int node = b * 256 + tid;
        if (node < N_NODES) row_ptr[node] = segStart + excl;
        cur[tid] = segStart + excl;
    }
    __syncthreads();
    for (int i = tid; i < cnt; i += 1024) {
        uint2 p = seg[i];
        int pos = atomicAdd(&cur[p.x >> 16], 1);
        pairs[pos] = (p.x & 0xFFFFu) | ((unsigned int)f2bf(asfloat_u32(p.y)) << 16);
    }
}

// ---------------- GEMM, N=64(->40 valid), K=128, MFMA, fully-staged ----------------
// C64[M x 64](bf16) = A[M x 128](bf16) @ Wt2^T ; cols 40+ zero. 128B aligned rows.
#define LDP2 136
__global__ __launch_bounds__(256) void gemm_n64(const unsigned short* __restrict__ A,
                                                const unsigned short* __restrict__ Wt2,
                                                unsigned short* __restrict__ C, int M) {
    __shared__ unsigned short As[64 * LDP2];
    __shared__ unsigned short Bs[64 * LDP2];
    const int tid = threadIdx.x;
    const int wave = tid >> 6;
    const int lane = tid & 63;
    const int ln = lane & 15;
    const int quad = lane >> 4;
    const int row0 = blockIdx.x * 64;

#pragma unroll
    for (int i = 0; i < 4; ++i) {  // A: 64 rows x 128 = 1024 chunks of 8
        int q = tid + 256 * i;
        int r = q >> 4;
        int c = (q & 15) * 8;
        bf16x8 v;
        if (row0 + r < M) {
            v = *(const bf16x8*)(A + (size_t)(row0 + r) * 128 + c);
        } else {
#pragma unroll
            for (int j = 0; j < 8; ++j) v[j] = 0;
        }
        *(bf16x8*)&As[r * LDP2 + c] = v;
    }
#pragma unroll
    for (int i = 0; i < 4; ++i) {  // B: 64 rows x 128 = 1024 chunks of 8
        int q = tid + 256 * i;
        int r = q >> 4;
        int c = (q & 15) * 8;
        *(bf16x8*)&Bs[r * LDP2 + c] = *(const bf16x8*)(Wt2 + (size_t)r * 128 + c);
    }
    __syncthreads();

    f32x4 acc[4];
#pragma unroll
    for (int t = 0; t < 4; ++t) acc[t] = (f32x4){0.f, 0.f, 0.f, 0.f};

#pragma unroll
    for (int kc = 0; kc < 128; kc += 32) {
        bf16x8 a = *(const bf16x8*)&As[(wave * 16 + ln) * LDP2 + kc + quad * 8];
#pragma unroll
        for (int t = 0; t < 4; ++t) {
            bf16x8 b = *(const bf16x8*)&Bs[(t * 16 + ln) * LDP2 + kc + quad * 8];
            acc[t] = __builtin_amdgcn_mfma_f32_16x16x32_bf16(a, b, acc[t], 0, 0, 0);
        }
    }

#pragma unroll
    for (int t = 0; t < 4; ++t) {
#pragma unroll
        for (int r = 0; r < 4; ++r) {
            int row = row0 + wave * 16 + quad * 4 + r;
            if (row < M) C[(size_t)row * 64 + t * 16 + ln] = f2bf(acc[t][r]);
        }
    }
}

// ---------------- SpMM (CSR gather, fp8 rows 128B) + bias + ReLU, feat=128 ----------
// One wave per dst node, FOUR 16-lane groups; group g gathers edge e+4i+g with a
// full 128B fp8 row (16 lanes x 8B uint2) -> 4 edges/instr, 32 in flight/wave.
// fp8 tables HALVE the L3 gather traffic vs bf16 (r1-r3: MLP scaling was null ->
// the bound is memory service; bytes/transactions are the lever).
__global__ __launch_bounds__(256) void spmm_bias_relu_fp8(const unsigned char* __restrict__ t,
                                                          const int* __restrict__ row_ptr,
                                                          const unsigned int* __restrict__ pairs,
                                                          const float* __restrict__ bias,
                                                          unsigned short* __restrict__ out) {
    const int node = blockIdx.x * 4 + (threadIdx.x >> 6);
    const int lane = threadIdx.x & 63;
    const int g = lane >> 4;        // group 0..3
    const int fl = (lane & 15) * 8; // feature base: 8 fp8 = 8B owned by this lane
    const int e0 = row_ptr[node];
    const int e1 = row_ptr[node + 1];
    float acc8[8];
#pragma unroll
    for (int j = 0; j < 8; ++j) acc8[j] = 0.f;

    int e = e0;
    for (; e + 32 <= e1; e += 32) {
        unsigned int p[8];
        uint2 v[8];
#pragma unroll
        for (int i = 0; i < 8; ++i) p[i] = pairs[e + 4 * i + g];
#pragma unroll
        for (int i = 0; i < 8; ++i)
            v[i] = *(const uint2*)(t + (size_t)(p[i] & 0xFFFFu) * 128 + fl);
#pragma unroll
        for (int i = 0; i < 8; ++i) {
            float w = asfloat_u32(p[i] & 0xFFFF0000u);
            float f[8];
            dq4(v[i].x, f);
            dq4(v[i].y, f + 4);
#pragma unroll
            for (int j = 0; j < 8; ++j) acc8[j] += w * f[j];
        }
    }
    for (; e + 4 <= e1; e += 4) {
        unsigned int p = pairs[e + g];
        uint2 v = *(const uint2*)(t + (size_t)(p & 0xFFFFu) * 128 + fl);
        float w = asfloat_u32(p & 0xFFFF0000u);
        float f[8];
        dq4(v.x, f);
        dq4(v.y, f + 4);
#pragma unroll
        for (int j = 0; j < 8; ++j) acc8[j] += w * f[j];
    }
    if (g < e1 - e) {  // remainder 0..3 edges, one per group
        unsigned int p = pairs[e + g];
        uint2 v = *(const uint2*)(t + (size_t)(p & 0xFFFFu) * 128 + fl);
        float w = asfloat_u32(p & 0xFFFF0000u);
        float f[8];
        dq4(v.x, f);
        dq4(v.y, f + 4);
#pragma unroll
        for (int j = 0; j < 8; ++j) acc8[j] += w * f[j];
    }
    // lanes l, l^16, l^32, l^48 own the same 8 features -> butterfly over groups
#pragma unroll
    for (int j = 0; j < 8; ++j) {
        acc8[j] += __shfl_xor(acc8[j], 16);
        acc8[j] += __shfl_xor(acc8[j], 32);
    }
    if (g == 0) {
        float4 b0 = *(const float4*)&bias[fl];
        float4 b1 = *(const float4*)&bias[fl + 4];
        acc8[0] = fmaxf(acc8[0] + b0.x, 0.f);
        acc8[1] = fmaxf(acc8[1] + b0.y, 0.f);
        acc8[2] = fmaxf(acc8[2] + b0.z, 0.f);
        acc8[3] = fmaxf(acc8[3] + b0.w, 0.f);
        acc8[4] = fmaxf(acc8[4] + b1.x, 0.f);
        acc8[5] = fmaxf(acc8[5] + b1.y, 0.f);
        acc8[6] = fmaxf(acc8[6] + b1.z, 0.f);
        acc8[7] = fmaxf(acc8[7] + b1.w, 0.f);
        uint4 o;
        o.x = ((unsigned int)f2bf(acc8[0])) | (((unsigned int)f2bf(acc8[1])) << 16);
        o.y = ((unsigned int)f2bf(acc8[2])) | (((unsigned int)f2bf(acc8[3])) << 16);
        o.z = ((unsigned int)f2bf(acc8[4])) | (((unsigned int)f2bf(acc8[5])) << 16);
        o.w = ((unsigned int)f2bf(acc8[6])) | (((unsigned int)f2bf(acc8[7])) << 16);
        *(uint4*)(out + (size_t)node * 128 + fl) = o;
    }
}

// ---------------- SpMM feat=64pad (bf16 rows) + bias + log_softmax ----------------
// t rows are 64 bf16 = 128B aligned (cols 40+ zero). FOUR 16-lane groups, each
// gathers a full row via uint2 -> 4 edges/instr, 32 in flight. Lane l&15 owns
// classes 4l..4l+3; lanes with (lane&15)>=10 hold only pad classes.
__global__ __launch_bounds__(256) void spmm_logsoftmax(const unsigned short* __restrict__ t,
                                                       const int* __restrict__ row_ptr,
                                                       const unsigned int* __restrict__ pairs,
                                                       const float* __restrict__ bias,
                                                       float* __restrict__ out) {
    const int node = blockIdx.x * 4 + (threadIdx.x >> 6);
    const int lane = threadIdx.x & 63;
    const int g = lane >> 4;
    const int fe = (lane & 15) * 4;  // element base (4 bf16 = 8B)
    const int e0 = row_ptr[node];
    const int e1 = row_ptr[node + 1];
    float a0 = 0.f, a1 = 0.f, a2 = 0.f, a3 = 0.f;
    int e = e0;
    for (; e + 32 <= e1; e += 32) {
        unsigned int p[8];
        uint2 v[8];
#pragma unroll
        for (int i = 0; i < 8; ++i) p[i] = pairs[e + 4 * i + g];
#pragma unroll
        for (int i = 0; i < 8; ++i)
            v[i] = *(const uint2*)(t + (size_t)(p[i] & 0xFFFFu) * 64 + fe);
#pragma unroll
        for (int i = 0; i < 8; ++i) {
            float w = asfloat_u32(p[i] & 0xFFFF0000u);
            a0 += w * asfloat_u32(v[i].x << 16);
            a1 += w * asfloat_u32(v[i].x & 0xFFFF0000u);
            a2 += w * asfloat_u32(v[i].y << 16);
            a3 += w * asfloat_u32(v[i].y & 0xFFFF0000u);
        }
    }
    for (; e + 4 <= e1; e += 4) {
        unsigned int p = pairs[e + g];
        uint2 v = *(const uint2*)(t + (size_t)(p & 0xFFFFu) * 64 + fe);
        float w = asfloat_u32(p & 0xFFFF0000u);
        a0 += w * asfloat_u32(v.x << 16);
        a1 += w * asfloat_u32(v.x & 0xFFFF0000u);
        a2 += w * asfloat_u32(v.y << 16);
        a3 += w * asfloat_u32(v.y & 0xFFFF0000u);
    }
    if (g < e1 - e) {
        unsigned int p = pairs[e + g];
        uint2 v = *(const uint2*)(t + (size_t)(p & 0xFFFFu) * 64 + fe);
        float w = asfloat_u32(p & 0xFFFF0000u);
        a0 += w * asfloat_u32(v.x << 16);
        a1 += w * asfloat_u32(v.x & 0xFFFF0000u);
        a2 += w * asfloat_u32(v.y << 16);
        a3 += w * asfloat_u32(v.y & 0xFFFF0000u);
    }
    a0 += __shfl_xor(a0, 16); a0 += __shfl_xor(a0, 32);
    a1 += __shfl_xor(a1, 16); a1 += __shfl_xor(a1, 32);
    a2 += __shfl_xor(a2, 16); a2 += __shfl_xor(a2, 32);
    a3 += __shfl_xor(a3, 16); a3 += __shfl_xor(a3, 32);

    const bool valid = (lane & 15) < 10;  // classes fe..fe+3 < 40
    float l0 = -INFINITY, l1 = -INFINITY, l2 = -INFINITY, l3 = -INFINITY;
    if (valid) {
        float4 b = *(const float4*)&bias[fe];
        l0 = a0 + b.x; l1 = a1 + b.y; l2 = a2 + b.z; l3 = a3 + b.w;
    }
    float m = fmaxf(fmaxf(l0, l1), fmaxf(l2, l3));
#pragma unroll
    for (int off = 8; off; off >>= 1) m = fmaxf(m, __shfl_xor(m, off));
    float s = valid ? (__expf(l0 - m) + __expf(l1 - m) + __expf(l2 - m) + __expf(l3 - m)) : 0.f;
#pragma unroll
    for (int off = 8; off; off >>= 1) s += __shfl_xor(s, off);
    if (valid && g == 0) {
        float ls = __logf(s);
        float4 o;
        o.x = l0 - m - ls; o.y = l1 - m - ls; o.z = l2 - m - ls; o.w = l3 - m - ls;
        *(float4*)&out[(size_t)node * NCLASS + fe] = o;
    }
}

// ---------------- launch ----------------

extern "C" void kernel_launch(void* const* d_in, const int* in_sizes, int n_in,
                              void* d_out, int out_size, void* d_ws, size_t ws_size,
                              hipStream_t stream) {
    const float* x = (const float*)d_in[0];
    const int* edge_src = (const int*)d_in[1];
    const int* edge_dst = (const int*)d_in[2];
    const float* edge_weight = (const float*)d_in[3];
    const float* W1 = (const float*)d_in[4];
    const float* b1 = (const float*)d_in[5];
    const float* Wh = (const float*)d_in[6];
    const float* bh = (const float*)d_in[7];
    const float* W2 = (const float*)d_in[8];
    const float* b2 = (const float*)d_in[9];
    float* out = (float*)d_out;

    size_t off = 0;
    auto carve = [&](size_t bytes) {
        void* p = (char*)d_ws + off;
        off += (bytes + 511) & ~(size_t)511;
        return p;
    };
    unsigned char* tb = (unsigned char*)carve((size_t)N_NODES * 128);   // fp8 table (t / t2)
    unsigned short* hb = (unsigned short*)carve((size_t)N_NODES * 128 * 2);
    unsigned short* t3 = (unsigned short*)carve((size_t)N_NODES * 64 * 2);
    unsigned short* Wt1 = (unsigned short*)carve((size_t)NFEAT * NHID * 2);
    unsigned short* Wth = (unsigned short*)carve((size_t)NHID * NHID * 2);
    unsigned short* Wt2 = (unsigned short*)carve((size_t)64 * NHID * 2);
    int* row_ptr = (int*)carve((size_t)(N_NODES + 4) * 4);
    int* bucketCursor = (int*)carve((size_t)NBUCKETS * 4);
    uint2* binned = (uint2*)carve((size_t)NBUCKETS * BUCKET_CAP * 8);
    unsigned int* pairs = (unsigned int*)carve((size_t)N_EDGES * 4);
    (void)ws_size; (void)n_in; (void)in_sizes; (void)out_size;

    const int prepBlocks =
        (NFEAT * NHID + NHID * NHID + 64 * NHID + NBUCKETS + 255) / 256;  // 353
    const int spmmBlocks = N_NODES / 4;            // 12500
    const int gemmBlocks = (N_NODES + 63) / 64;    // 782

    // prep (weights + cursors)
    prep_kernel<<<prepBlocks, 256, 0, stream>>>(W1, Wt1, Wh, Wth, W2, Wt2, bucketCursor);

    // GEMM1 || bin (independent work fused into one launch)
    fused_gemm1_bin<<<GEMM1_BLOCKS + BIN_BLOCKS, 256, 0, stream>>>(
        x, Wt1, tb, edge_src, edge_dst, edge_weight, bucketCursor, binned);

    // CSR finalize (inline bucket scan; 1024 thr -- 196 blocks are latency-critical)
    build_csr<<<NBUCKETS, 1024, 0, stream>>>(binned, bucketCursor, pairs, row_ptr);

    // Layer 1 aggregate (fp8 table -> bf16 hidden)
    spmm_bias_relu_fp8<<<spmmBlocks, 256, 0, stream>>>(tb, row_ptr, pairs, b1, hb);

    // Layer 2
    gemm64_l2<<<gemmBlocks, 256, 0, stream>>>(hb, Wth, tb);
    spmm_bias_relu_fp8<<<spmmBlocks, 256, 0, stream>>>(tb, row_ptr, pairs, bh, hb);

    // Layer 3 (MFMA, fully-staged tiles, 64-col padded bf16 output)
    gemm_n64<<<gemmBlocks, 256, 0, stream>>>(hb, Wt2, t3, N_NODES);
    spmm_logsoftmax<<<spmmBlocks, 256, 0, stream>>>(t3, row_ptr, pairs, b2, out);
}